// Round 10
// baseline (1188.590 us; speedup 1.0000x reference)
//
#include <hip/hip_runtime.h>
#include <hip/hip_bf16.h>

typedef __hip_bfloat16 bf16;
typedef __attribute__((ext_vector_type(8))) short frag8;   // 8 bf16 = 4 VGPRs
typedef __attribute__((ext_vector_type(4))) float f32x4;

#define BM 128
#define BN 128
#define BK 64
#define SK 72   // padded LDS stride for VGPR-staged kernels

__device__ __forceinline__ float sigm(float x) { return 1.f / (1.f + __expf(-x)); }

// async global->LDS, 16B/lane; lds base wave-uniform, lane scatters at +lane*16
__device__ __forceinline__ void lds_load16(const bf16* g, short* l) {
    __builtin_amdgcn_global_load_lds(
        (const __attribute__((address_space(1))) void*)g,
        (__attribute__((address_space(3))) void*)l, 16, 0, 0);
}

// C[m,n] = sum_k A[m,k] * W[n,k]; 128x128 tile, padded in-loop VGPR staging (no prefetch
// regs: r5/r6 spill lesson). Used for hoisted ipre0 GEMM and the K-split final GEMM.
// outmode: 0 fp32, 1 bf16, 2 sigmoid(acc+bias[n]) fp32 n<nbound, 3 raw fp32 n<nbound.
__global__ __launch_bounds__(256, 2)
void gemm_bt(const bf16* __restrict__ A, int lda, long long sAz,
             const bf16* __restrict__ W, int ldw, long long sWz,
             void* __restrict__ Cv, int ldc, long long sCz, int K,
             int outmode, const float* __restrict__ bias, int nbound)
{
    __shared__ short As[BM * SK];
    __shared__ short Bs[BN * SK];
    const int z = blockIdx.z;
    A += (size_t)z * sAz;
    W += (size_t)z * sWz;
    const int m0 = blockIdx.y * BM;
    const int n0 = blockIdx.x * BN;
    const int tid  = threadIdx.x;
    const int lane = tid & 63;
    const int wave = tid >> 6;
    const int wm = (wave >> 1) * 64;
    const int wn = (wave & 1) * 64;
    const int q   = lane >> 4;
    const int r16 = lane & 15;

    f32x4 acc[4][4] = {};

    const int trow = tid >> 3;         // 0..31
    const int tcol = (tid & 7) * 8;    // 16B chunk (bf16 elems)

    for (int k0 = 0; k0 < K; k0 += BK) {
        __syncthreads();
        #pragma unroll
        for (int p = 0; p < 4; ++p) {
            int rr = p * 32 + trow;
            *(uint4*)&As[rr * SK + tcol] =
                *(const uint4*)(A + (size_t)(m0 + rr) * lda + k0 + tcol);
            *(uint4*)&Bs[rr * SK + tcol] =
                *(const uint4*)(W + (size_t)(n0 + rr) * ldw + k0 + tcol);
        }
        __syncthreads();
        #pragma unroll
        for (int kk = 0; kk < 2; ++kk) {
            const int ko = kk * 32 + q * 8;
            frag8 af[4], bfr[4];
            #pragma unroll
            for (int i = 0; i < 4; ++i)
                af[i] = *(const frag8*)&As[(wm + i * 16 + r16) * SK + ko];
            #pragma unroll
            for (int j = 0; j < 4; ++j)
                bfr[j] = *(const frag8*)&Bs[(wn + j * 16 + r16) * SK + ko];
            #pragma unroll
            for (int i = 0; i < 4; ++i)
                #pragma unroll
                for (int j = 0; j < 4; ++j)
                    acc[i][j] = __builtin_amdgcn_mfma_f32_16x16x32_bf16(
                        af[i], bfr[j], acc[i][j], 0, 0, 0);
        }
    }

    if (outmode == 0) {
        float* C = (float*)Cv + (size_t)z * sCz;
        #pragma unroll
        for (int i = 0; i < 4; ++i)
            #pragma unroll
            for (int rr = 0; rr < 4; ++rr) {
                int row = m0 + wm + i * 16 + q * 4 + rr;
                float* crow = C + (size_t)row * ldc + n0 + wn + r16;
                #pragma unroll
                for (int j = 0; j < 4; ++j) crow[j * 16] = acc[i][j][rr];
            }
    } else if (outmode == 1) {
        bf16* C = (bf16*)Cv + (size_t)z * sCz;
        #pragma unroll
        for (int i = 0; i < 4; ++i)
            #pragma unroll
            for (int rr = 0; rr < 4; ++rr) {
                int row = m0 + wm + i * 16 + q * 4 + rr;
                bf16* crow = C + (size_t)row * ldc + n0 + wn + r16;
                #pragma unroll
                for (int j = 0; j < 4; ++j) crow[j * 16] = __float2bfloat16(acc[i][j][rr]);
            }
    } else if (outmode == 2) {
        float* C = (float*)Cv + (size_t)z * sCz;
        #pragma unroll
        for (int i = 0; i < 4; ++i)
            #pragma unroll
            for (int rr = 0; rr < 4; ++rr) {
                int row = m0 + wm + i * 16 + q * 4 + rr;
                #pragma unroll
                for (int j = 0; j < 4; ++j) {
                    int col = n0 + wn + j * 16 + r16;
                    if (col < nbound)
                        C[(size_t)row * ldc + col] = sigm(acc[i][j][rr] + bias[col]);
                }
            }
    } else {
        float* C = (float*)Cv + (size_t)z * sCz;
        #pragma unroll
        for (int i = 0; i < 4; ++i)
            #pragma unroll
            for (int rr = 0; rr < 4; ++rr) {
                int row = m0 + wm + i * 16 + q * 4 + rr;
                #pragma unroll
                for (int j = 0; j < 4; ++j) {
                    int col = n0 + wn + j * 16 + r16;
                    if (col < nbound)
                        C[(size_t)row * ldc + col] = acc[i][j][rr];
                }
            }
    }
}

// ---------------- merged hidden-side kernel (async staging + XOR-swizzled LDS) ----------------
// Grid (36, 32): zi = x%6, xt = x/6. LDS layout: row R's k-chunk c sits at position
// c ^ (R&7)  ->  quad fragment reads hit all 32 banks at 2 lanes/bank (free, m136),
// vs 16-way conflict of the linear layout (7.2M conflicts/dispatch in r9).
__global__ __launch_bounds__(256, 4)
void gemm_hidden(const bf16* __restrict__ hprev,
                 const bf16* __restrict__ WhFIO,  // [3][768][256]
                 const bf16* __restrict__ WhCb,   // [3][768][768]
                 const bf16* __restrict__ WgH,    // [3][16][768], rows 0..2 = Wh_g[l]
                 const float* __restrict__ big, const float* __restrict__ bhg,  // [9]
                 bf16* __restrict__ hgb,          // [3][4096][768]
                 bf16* __restrict__ auxb,         // [3][4096][768]
                 float* __restrict__ gh)          // [4096][9]
{
    __shared__ __align__(16) short As[BM * 64];
    __shared__ __align__(16) short Bs[BN * 64];
    __shared__ __align__(16) short Bg[16 * 64];

    const int zi = blockIdx.x % 6;
    const int xt = blockIdx.x / 6;
    const bool isaux = zi >= 3;
    const int l = isaux ? zi - 3 : zi;
    const bf16* A = hprev + (isaux ? 0 : l * 256);
    const int K = isaux ? 768 : 256;
    const bf16* W = isaux ? (WhCb + (size_t)l * 768 * 768) : (WhFIO + (size_t)l * 768 * 256);
    const int ldw = isaux ? 768 : 256;
    bf16* C = (isaux ? auxb : hgb) + (size_t)l * 4096 * 768;
    const bool do_g = isaux && (xt == 0);

    const int m0 = blockIdx.y * BM;
    const int n0 = xt * BN;
    const int tid  = threadIdx.x;
    const int lane = tid & 63;
    const int wave = tid >> 6;
    const int wm = (wave >> 1) * 64;
    const int wn = (wave & 1) * 64;
    const int q   = lane >> 4;
    const int r16 = lane & 15;

    f32x4 acc[4][4] = {};
    f32x4 accg[4] = {};

    const int srow = lane >> 3;                      // 0..7 row within 8-row chunk
    const int scolsw = ((lane & 7) ^ srow) * 8;      // XOR-swizzled source chunk
    const bf16* WgL = WgH + (size_t)l * 16 * 768;

    for (int k0 = 0; k0 < K; k0 += BK) {
        __syncthreads();
        #pragma unroll
        for (int p = 0; p < 4; ++p) {
            int rbase = (wave * 4 + p) * 8;
            lds_load16(A + (size_t)(m0 + rbase + srow) * 768 + k0 + scolsw, &As[rbase * 64]);
            lds_load16(W + (size_t)(n0 + rbase + srow) * ldw + k0 + scolsw, &Bs[rbase * 64]);
        }
        if (do_g && wave < 2)
            lds_load16(WgL + (size_t)(wave * 8 + srow) * 768 + k0 + scolsw, &Bg[wave * 8 * 64]);
        __syncthreads();
        #pragma unroll
        for (int kk = 0; kk < 2; ++kk) {
            const int c = kk * 4 + q;   // k-chunk index 0..7
            frag8 af[4], bfr[4];
            #pragma unroll
            for (int i = 0; i < 4; ++i) {
                int R = wm + i * 16 + r16;
                af[i] = *(const frag8*)&As[R * 64 + ((c ^ (R & 7)) << 3)];
            }
            #pragma unroll
            for (int j = 0; j < 4; ++j) {
                int R = wn + j * 16 + r16;
                bfr[j] = *(const frag8*)&Bs[R * 64 + ((c ^ (R & 7)) << 3)];
            }
            #pragma unroll
            for (int i = 0; i < 4; ++i)
                #pragma unroll
                for (int j = 0; j < 4; ++j)
                    acc[i][j] = __builtin_amdgcn_mfma_f32_16x16x32_bf16(
                        af[i], bfr[j], acc[i][j], 0, 0, 0);
            if (do_g) {
                frag8 bg = *(const frag8*)&Bg[r16 * 64 + ((c ^ (r16 & 7)) << 3)];
                #pragma unroll
                for (int i = 0; i < 4; ++i)
                    accg[i] = __builtin_amdgcn_mfma_f32_16x16x32_bf16(
                        af[i], bg, accg[i], 0, 0, 0);
            }
        }
    }

    #pragma unroll
    for (int i = 0; i < 4; ++i)
        #pragma unroll
        for (int rr = 0; rr < 4; ++rr) {
            int row = m0 + wm + i * 16 + q * 4 + rr;
            bf16* crow = C + (size_t)row * 768 + n0 + wn + r16;
            #pragma unroll
            for (int j = 0; j < 4; ++j) crow[j * 16] = __float2bfloat16(acc[i][j][rr]);
        }
    if (do_g && wn == 0 && r16 < 3) {
        float bsum = big[l * 3 + r16] + bhg[l * 3 + r16];
        #pragma unroll
        for (int i = 0; i < 4; ++i)
            #pragma unroll
            for (int rr = 0; rr < 4; ++rr) {
                int row = m0 + wm + i * 16 + q * 4 + rr;
                gh[(size_t)row * 9 + l * 3 + r16] = accg[i][rr] + bsum;
            }
    }
}

// ---------------- fused input-GEMM + gates (layers 1,2) ----------------
// 64m x 128n tile, grid (8, 64) = 512 blocks = 2/CU. Async staging + XOR swizzle.
#define GM 64
struct Stage { short As[GM * 64]; short Bs[BN * 64]; short Bg[16 * 64]; };
union SMemU { Stage s; float ct[GM * 128]; };

__global__ __launch_bounds__(256, 2)
void gemm_gates(const bf16* __restrict__ A, int lda,
                const bf16* __restrict__ Wi, const bf16* __restrict__ Wg,
                const bf16* __restrict__ hg_l,   // [4096][768] bf16
                const bf16* __restrict__ aux_l,  // [4096][768] bf16
                const float* __restrict__ ghc_l, // gh + l*3, stride 9, biases folded
                const float* __restrict__ cprev,
                const float* __restrict__ bif, const float* __restrict__ bhf,
                const float* __restrict__ bii, const float* __restrict__ bhi,
                const float* __restrict__ bio, const float* __restrict__ bho,
                const float* __restrict__ bic, const float* __restrict__ bhc, // [768]
                bf16*  __restrict__ hnew,   // col-slice base, row stride 768
                float* __restrict__ cnew,
                bf16*  __restrict__ featc)  // nullable, row stride 2304
{
    __shared__ __align__(16) SMemU sm;
    __shared__ float gsh[GM * 3];

    const int m0 = blockIdx.y * GM;
    const int n0 = blockIdx.x * BN;
    const int jbase = n0 >> 2;
    const int tid  = threadIdx.x;
    const int lane = tid & 63;
    const int wave = tid >> 6;
    const int wm = (wave >> 1) * 32;   // 2x2 waves, each 32m x 64n
    const int wn = (wave & 1) * 64;
    const int q   = lane >> 4;
    const int r16 = lane & 15;

    f32x4 acc[2][4] = {};
    f32x4 accg[2] = {};

    const int srow = lane >> 3;
    const int scolsw = ((lane & 7) ^ srow) * 8;

    for (int k0 = 0; k0 < 256; k0 += BK) {
        __syncthreads();
        #pragma unroll
        for (int p = 0; p < 2; ++p) {
            int rbase = (wave * 2 + p) * 8;   // A: 64 rows = 8 chunks
            lds_load16(A + (size_t)(m0 + rbase + srow) * lda + k0 + scolsw, &sm.s.As[rbase * 64]);
        }
        #pragma unroll
        for (int p = 0; p < 4; ++p) {
            int rbase = (wave * 4 + p) * 8;   // B: 128 rows = 16 chunks
            lds_load16(Wi + (size_t)(n0 + rbase + srow) * 256 + k0 + scolsw, &sm.s.Bs[rbase * 64]);
        }
        if (wave < 2)
            lds_load16(Wg + (size_t)(wave * 8 + srow) * 256 + k0 + scolsw, &sm.s.Bg[wave * 8 * 64]);
        __syncthreads();
        #pragma unroll
        for (int kk = 0; kk < 2; ++kk) {
            const int c = kk * 4 + q;
            frag8 af[2], bfr[4], bg;
            bg = *(const frag8*)&sm.s.Bg[r16 * 64 + ((c ^ (r16 & 7)) << 3)];
            #pragma unroll
            for (int i = 0; i < 2; ++i) {
                int R = wm + i * 16 + r16;
                af[i] = *(const frag8*)&sm.s.As[R * 64 + ((c ^ (R & 7)) << 3)];
            }
            #pragma unroll
            for (int j = 0; j < 4; ++j) {
                int R = wn + j * 16 + r16;
                bfr[j] = *(const frag8*)&sm.s.Bs[R * 64 + ((c ^ (R & 7)) << 3)];
            }
            #pragma unroll
            for (int i = 0; i < 2; ++i) {
                #pragma unroll
                for (int j = 0; j < 4; ++j)
                    acc[i][j] = __builtin_amdgcn_mfma_f32_16x16x32_bf16(
                        af[i], bfr[j], acc[i][j], 0, 0, 0);
                accg[i] = __builtin_amdgcn_mfma_f32_16x16x32_bf16(
                    af[i], bg, accg[i], 0, 0, 0);
            }
        }
    }

    __syncthreads();   // staging reads done; sm union becomes ct
    // g values: waves with wn==0 (0 and 2) cover rows 0..63
    if (wn == 0 && r16 < 3) {
        #pragma unroll
        for (int i = 0; i < 2; ++i)
            #pragma unroll
            for (int rr = 0; rr < 4; ++rr) {
                int row = wm + i * 16 + q * 4 + rr;
                gsh[row * 3 + r16] = sigm(accg[i][rr] + ghc_l[(size_t)(m0 + row) * 9 + r16]);
            }
    }
    // dump C tile (rotate-swizzled float4 groups)
    #pragma unroll
    for (int i = 0; i < 2; ++i)
        #pragma unroll
        for (int rr = 0; rr < 4; ++rr) {
            int rowl = wm + i * 16 + q * 4 + rr;
            #pragma unroll
            for (int jr = 0; jr < 4; ++jr) {
                int col = wn + jr * 16 + r16;
                sm.ct[rowl * 128 + ((col + 4 * rowl) & 127)] = acc[i][jr][rr];
            }
        }
    __syncthreads();

    const int jj = tid & 31;
    const int r0 = (tid >> 5) * 8;
    const int j  = jbase + jj;
    const float vbif = bif[j], vbhf = bhf[j];
    const float vbii = bii[j], vbhi = bhi[j];
    const float vbio = bio[j], vbho = bho[j];
    const float vbic = bic[j];
    const float vbc0 = bhc[j], vbc1 = bhc[256 + j], vbc2 = bhc[512 + j];

    for (int ri = 0; ri < 8; ++ri) {
        int rowl = r0 + ri;
        size_t b = m0 + rowl;
        float4 pre = *(float4*)&sm.ct[rowl * 128 + ((4 * jj + 4 * rowl) & 127)];
        float g0 = gsh[rowl * 3 + 0];
        float g1 = gsh[rowl * 3 + 1];
        float g2 = gsh[rowl * 3 + 2];
        float hgf = __bfloat162float(hg_l[b * 768 + j]);
        float hgi = __bfloat162float(hg_l[b * 768 + 256 + j]);
        float hgo = __bfloat162float(hg_l[b * 768 + 512 + j]);
        float ax0 = __bfloat162float(aux_l[b * 768 + j]);
        float ax1 = __bfloat162float(aux_l[b * 768 + 256 + j]);
        float ax2 = __bfloat162float(aux_l[b * 768 + 512 + j]);
        float f  = sigm(pre.x + vbif + hgf + vbhf);
        float ii = sigm(pre.y + vbii + hgi + vbhi);
        float o  = sigm(pre.z + vbio + hgo + vbho);
        float av = g0 * (ax0 + vbc0) + g1 * (ax1 + vbc1) + g2 * (ax2 + vbc2);
        float ct = tanhf(pre.w + vbic + av);
        float c  = f * cprev[b * 256 + j] + ii * ct;
        float h  = o * c;
        cnew[b * 256 + j] = c;
        hnew[b * 768 + j] = __float2bfloat16(h);
        if (featc) featc[b * 2304 + j] = __float2bfloat16(h);
    }
}

// ---------------- layer-0 gates from precomputed pre-acts ----------------
// 1024 blocks x 4 rows
__global__ __launch_bounds__(256)
void gates_pre(const bf16* __restrict__ ipre0i, const float* __restrict__ gin0,
               const float* __restrict__ ghc,
               const bf16* __restrict__ hg_l, const bf16* __restrict__ aux_l,
               const float* __restrict__ cprev,
               const float* __restrict__ bif, const float* __restrict__ bhf,
               const float* __restrict__ bii, const float* __restrict__ bhi,
               const float* __restrict__ bio, const float* __restrict__ bho,
               const float* __restrict__ bic, const float* __restrict__ bhc,
               bf16* __restrict__ hnew, float* __restrict__ cnew)
{
    const int j = threadIdx.x;
    const int b0 = blockIdx.x * 4;
    const float vbif = bif[j], vbhf = bhf[j];
    const float vbii = bii[j], vbhi = bhi[j];
    const float vbio = bio[j], vbho = bho[j];
    const float vbic = bic[j];
    const float vbc0 = bhc[j], vbc1 = bhc[256 + j], vbc2 = bhc[512 + j];

    #pragma unroll
    for (int r = 0; r < 4; ++r) {
        const size_t b = b0 + r;
        const bf16* ip4 = ipre0i + b * 1024 + 4 * j;
        float pf = __bfloat162float(ip4[0]);
        float pi = __bfloat162float(ip4[1]);
        float po = __bfloat162float(ip4[2]);
        float pc = __bfloat162float(ip4[3]);
        float g0 = sigm(gin0[b * 3 + 0] + ghc[b * 9 + 0]);
        float g1 = sigm(gin0[b * 3 + 1] + ghc[b * 9 + 1]);
        float g2 = sigm(gin0[b * 3 + 2] + ghc[b * 9 + 2]);
        float hgf = __bfloat162float(hg_l[b * 768 + j]);
        float hgi = __bfloat162float(hg_l[b * 768 + 256 + j]);
        float hgo = __bfloat162float(hg_l[b * 768 + 512 + j]);
        float ax0 = __bfloat162float(aux_l[b * 768 + j]);
        float ax1 = __bfloat162float(aux_l[b * 768 + 256 + j]);
        float ax2 = __bfloat162float(aux_l[b * 768 + 512 + j]);
        float f  = sigm(pf + vbif + hgf + vbhf);
        float ii = sigm(pi + vbii + hgi + vbhi);
        float o  = sigm(po + vbio + hgo + vbho);
        float av = g0 * (ax0 + vbc0) + g1 * (ax1 + vbc1) + g2 * (ax2 + vbc2);
        float ct = tanhf(pc + vbic + av);
        float c  = f * cprev[b * 256 + j] + ii * ct;
        float h  = o * c;
        cnew[b * 256 + j] = c;
        hnew[b * 768 + j] = __float2bfloat16(h);
    }
}

// gin0[b][s] = xb[b,:] . Wi_g[0][s][:]  (no bias; constant over t)
__global__ __launch_bounds__(256)
void gin0_kernel(const bf16* __restrict__ xb, const float* __restrict__ Wig,
                 float* __restrict__ gout)
{
    const int wave = threadIdx.x >> 6, lane = threadIdx.x & 63;
    for (int rep = 0; rep < 4; ++rep) {
        size_t b = (size_t)blockIdx.x * 16 + wave * 4 + rep;
        float hv[4];
        #pragma unroll
        for (int m = 0; m < 4; ++m)
            hv[m] = __bfloat162float(xb[b * 256 + m * 64 + lane]);
        float p[3];
        #pragma unroll
        for (int s = 0; s < 3; ++s) {
            float t = 0.f;
            const float* w = Wig + (size_t)s * 256;
            #pragma unroll
            for (int m = 0; m < 4; ++m) t += hv[m] * w[m * 64 + lane];
            p[s] = t;
        }
        #pragma unroll
        for (int off = 32; off; off >>= 1)
            #pragma unroll
            for (int s = 0; s < 3; ++s) p[s] += __shfl_down(p[s], off);
        if (lane == 0) {
            #pragma unroll
            for (int s = 0; s < 3; ++s) gout[b * 3 + s] = p[s];
        }
    }
}

// out[b][n] = sigm(bias[n] + sum_z part[z][b][n]), n<44
__global__ __launch_bounds__(256)
void final_reduce(const float* __restrict__ part, const float* __restrict__ bl,
                  float* __restrict__ out)
{
    int idx = blockIdx.x * 256 + threadIdx.x;
    if (idx >= 4096 * 44) return;
    int b = idx / 44, n = idx - b * 44;
    float s = bl[n];
    #pragma unroll
    for (int z = 0; z < 12; ++z) s += part[(size_t)z * 4096 * 64 + (size_t)b * 64 + n];
    out[idx] = sigm(s);
}

// ---------------- prep kernels ----------------
__global__ void build_wicati(const float* __restrict__ Wf, const float* __restrict__ Wi,
                             const float* __restrict__ Wo, const float* __restrict__ Wc,
                             bf16* __restrict__ out)
{
    int idx = blockIdx.x * 256 + threadIdx.x;  // 3*1024*256
    int k = idx & 255, n = (idx >> 8) & 1023, l = idx >> 18;
    int j = n >> 2, g = n & 3;
    const float* src = (g == 0) ? Wf : (g == 1) ? Wi : (g == 2) ? Wo : Wc;
    out[idx] = __float2bfloat16(src[l * 65536 + j * 256 + k]);
}

__global__ void build_whfio(const float* __restrict__ Wf, const float* __restrict__ Wi,
                            const float* __restrict__ Wo, bf16* __restrict__ out)
{
    int idx = blockIdx.x * 256 + threadIdx.x;  // 3*768*256
    int k = idx & 255, n = (idx >> 8) % 768, l = idx / 196608;
    const float* src = (n < 256) ? Wf : (n < 512) ? Wi : Wo;
    out[idx] = __float2bfloat16(src[l * 65536 + (n & 255) * 256 + k]);
}

__global__ void build_wg(const float* __restrict__ Wig, bf16* __restrict__ out)
{
    int idx = blockIdx.x * 256 + threadIdx.x;  // 3*16*256
    int k = idx & 255, r = (idx >> 8) & 15, l = idx >> 12;
    out[idx] = (r < 3) ? __float2bfloat16(Wig[l * 768 + r * 256 + k]) : __float2bfloat16(0.f);
}

// WgH [3][16][768]: rows 0..2 = Wh_g[l], rest zero
__global__ void build_wgh(const float* __restrict__ Whg, bf16* __restrict__ out)
{
    int idx = blockIdx.x * 256 + threadIdx.x;  // 3*16*768
    int k = idx % 768, r = (idx / 768) & 15, l = idx / (16 * 768);
    out[idx] = (r < 3) ? __float2bfloat16(Whg[(l * 3 + r) * 768 + k]) : __float2bfloat16(0.f);
}

__global__ void build_wlast(const float* __restrict__ Wl, bf16* __restrict__ out)
{
    int idx = blockIdx.x * 256 + threadIdx.x;  // 128*2304
    int k = idx % 2304, n = idx / 2304;
    out[idx] = (n < 44) ? __float2bfloat16(Wl[n * 2304 + k]) : __float2bfloat16(0.f);
}

__global__ void convert_f2b(const float* __restrict__ in, bf16* __restrict__ out, int n)
{
    int idx = blockIdx.x * 256 + threadIdx.x;
    if (idx < n) out[idx] = __float2bfloat16(in[idx]);
}

__global__ void init_state(const float* __restrict__ hidden0, const float* __restrict__ current0,
                           bf16* __restrict__ hcat, float* __restrict__ c0)
{
    int idx = blockIdx.x * 256 + threadIdx.x;  // 3*4096*256
    int j = idx & 255, b = (idx >> 8) & 4095, l = idx >> 20;
    hcat[(size_t)b * 768 + l * 256 + j] = __float2bfloat16(hidden0[idx]);
    c0[idx] = current0[idx];
}

extern "C" void kernel_launch(void* const* d_in, const int* in_sizes, int n_in,
                              void* d_out, int out_size, void* d_ws, size_t ws_size,
                              hipStream_t stream)
{
    (void)in_sizes; (void)n_in; (void)out_size; (void)ws_size;
    const float* x        = (const float*)d_in[0];
    const float* hidden0  = (const float*)d_in[1];
    const float* current0 = (const float*)d_in[2];
    const float* Wi_f = (const float*)d_in[3];  const float* bi_f = (const float*)d_in[4];
    const float* Wi_i = (const float*)d_in[5];  const float* bi_i = (const float*)d_in[6];
    const float* Wi_o = (const float*)d_in[7];  const float* bi_o = (const float*)d_in[8];
    const float* Wi_c = (const float*)d_in[9];  const float* bi_c = (const float*)d_in[10];
    const float* Wi_g = (const float*)d_in[11]; const float* bi_g = (const float*)d_in[12];
    const float* Wh_f = (const float*)d_in[13]; const float* bh_f = (const float*)d_in[14];
    const float* Wh_i = (const float*)d_in[15]; const float* bh_i = (const float*)d_in[16];
    const float* Wh_o = (const float*)d_in[17]; const float* bh_o = (const float*)d_in[18];
    const float* Wh_g = (const float*)d_in[19]; const float* bh_g = (const float*)d_in[20];
    const float* Wh_c = (const float*)d_in[21]; const float* bh_c = (const float*)d_in[22];
    const float* W_last = (const float*)d_in[23]; const float* b_last = (const float*)d_in[24];

    char* p = (char*)d_ws;
    bf16* WiCatI = (bf16*)p; p += (size_t)3 * 1024 * 256 * 2;
    bf16* WhFIO  = (bf16*)p; p += (size_t)3 * 768 * 256 * 2;
    bf16* WhCb   = (bf16*)p; p += (size_t)3 * 768 * 768 * 2;
    bf16* Wgb    = (bf16*)p; p += (size_t)3 * 16 * 256 * 2;
    bf16* WgH    = (bf16*)p; p += (size_t)3 * 16 * 768 * 2;
    bf16* Wlb    = (bf16*)p; p += (size_t)128 * 2304 * 2;
    bf16* xb     = (bf16*)p; p += (size_t)4096 * 256 * 2;
    bf16* ipre0i = (bf16*)p; p += (size_t)4096 * 1024 * 2;
    float* gin0  = (float*)p; p += (size_t)4096 * 3 * 4;
    bf16* hb0    = (bf16*)p; p += (size_t)4096 * 768 * 2;
    bf16* hb1    = (bf16*)p; p += (size_t)4096 * 768 * 2;
    float* cb0   = (float*)p; p += (size_t)3 * 4096 * 256 * 4;
    float* cb1   = (float*)p; p += (size_t)3 * 4096 * 256 * 4;
    bf16* hgb    = (bf16*)p; p += (size_t)3 * 4096 * 768 * 2;
    bf16* auxb   = (bf16*)p; p += (size_t)3 * 4096 * 768 * 2;
    float* gh    = (float*)p; p += (size_t)4096 * 9 * 4;
    bf16* feat   = (bf16*)p; p += (size_t)4096 * 2304 * 2;
    float* partf = (float*)p; p += (size_t)12 * 4096 * 64 * 4;

    build_wicati<<<3072, 256, 0, stream>>>(Wi_f, Wi_i, Wi_o, Wi_c, WiCatI);
    build_whfio<<<2304, 256, 0, stream>>>(Wh_f, Wh_i, Wh_o, WhFIO);
    convert_f2b<<<(3 * 768 * 768 + 255) / 256, 256, 0, stream>>>(Wh_c, WhCb, 3 * 768 * 768);
    build_wg<<<48, 256, 0, stream>>>(Wi_g, Wgb);
    build_wgh<<<144, 256, 0, stream>>>(Wh_g, WgH);
    build_wlast<<<1152, 256, 0, stream>>>(W_last, Wlb);
    convert_f2b<<<4096, 256, 0, stream>>>(x, xb, 4096 * 256);
    init_state<<<12288, 256, 0, stream>>>(hidden0, current0, hb0, cb0);

    // hoisted layer-0 input-side work (x constant across t)
    gemm_bt<<<dim3(8, 32, 1), 256, 0, stream>>>(xb, 256, 0, WiCatI, 256, 0,
                                                ipre0i, 1024, 0, 256, 1, nullptr, 0);
    gin0_kernel<<<256, 256, 0, stream>>>(xb, Wi_g, gin0);

    for (int t = 0; t < 10; ++t) {
        bf16* hprev = (t & 1) ? hb1 : hb0;
        bf16* hnew  = (t & 1) ? hb0 : hb1;
        float* cprev = (t & 1) ? cb1 : cb0;
        float* cnew  = (t & 1) ? cb0 : cb1;

        gemm_hidden<<<dim3(36, 32), 256, 0, stream>>>(
            hprev, WhFIO, WhCb, WgH, bi_g, bh_g, hgb, auxb, gh);

        gates_pre<<<1024, 256, 0, stream>>>(
            ipre0i, gin0, gh,
            hgb, auxb, cprev,
            bi_f, bh_f, bi_i, bh_i, bi_o, bh_o, bi_c, bh_c,
            hnew, cnew);

        for (int l = 1; l < 3; ++l) {
            gemm_gates<<<dim3(8, 64), 256, 0, stream>>>(
                (const bf16*)(hnew + (l - 1) * 256), 768,
                WiCatI + (size_t)l * 1024 * 256,
                Wgb + (size_t)l * 16 * 256,
                hgb + (size_t)l * 4096 * 768,
                auxb + (size_t)l * 4096 * 768,
                gh + l * 3,
                cprev + (size_t)l * 4096 * 256,
                bi_f + l * 256, bh_f + l * 256,
                bi_i + l * 256, bh_i + l * 256,
                bi_o + l * 256, bh_o + l * 256,
                bi_c + l * 256, bh_c + l * 768,
                hnew + l * 256,
                cnew + (size_t)l * 4096 * 256,
                (l == 2 && t < 9) ? (feat + (size_t)t * 256) : (bf16*)nullptr);
        }
    }

    // final: K-split feat[4096,2304] @ Wlb[128,2304]^T into 12 partials of K=192
    gemm_bt<<<dim3(1, 32, 12), 256, 0, stream>>>(
        feat, 2304, 192, Wlb, 2304, 192,
        partf, 64, (long long)4096 * 64, 192, 3, nullptr, 64);
    final_reduce<<<704, 256, 0, stream>>>(partf, b_last, (float*)d_out);
}

// Round 11
// 853.237 us; speedup vs baseline: 1.3930x; 1.3930x over previous
//
#include <hip/hip_runtime.h>
#include <hip/hip_bf16.h>

typedef __hip_bfloat16 bf16;
typedef __attribute__((ext_vector_type(8))) short frag8;   // 8 bf16 = 4 VGPRs
typedef __attribute__((ext_vector_type(4))) float f32x4;

#define BM 128
#define BN 128
#define BK 64
#define SK 72   // padded LDS stride for VGPR-staged kernels

__device__ __forceinline__ float sigm(float x) { return 1.f / (1.f + __expf(-x)); }

// async global->LDS, 16B/lane; lds base wave-uniform, lane scatters at +lane*16
__device__ __forceinline__ void lds_load16(const bf16* g, short* l) {
    __builtin_amdgcn_global_load_lds(
        (const __attribute__((address_space(1))) void*)g,
        (__attribute__((address_space(3))) void*)l, 16, 0, 0);
}

// C[m,n] = sum_k A[m,k] * W[n,k]; 128x128 tile, padded in-loop VGPR staging.
// outmode: 0 fp32, 1 bf16, 2 sigmoid(acc+bias[n]) fp32 n<nbound, 3 raw fp32 n<nbound.
__global__ __launch_bounds__(256, 2)
void gemm_bt(const bf16* __restrict__ A, int lda, long long sAz,
             const bf16* __restrict__ W, int ldw, long long sWz,
             void* __restrict__ Cv, int ldc, long long sCz, int K,
             int outmode, const float* __restrict__ bias, int nbound)
{
    __shared__ short As[BM * SK];
    __shared__ short Bs[BN * SK];
    const int z = blockIdx.z;
    A += (size_t)z * sAz;
    W += (size_t)z * sWz;
    const int m0 = blockIdx.y * BM;
    const int n0 = blockIdx.x * BN;
    const int tid  = threadIdx.x;
    const int lane = tid & 63;
    const int wave = tid >> 6;
    const int wm = (wave >> 1) * 64;
    const int wn = (wave & 1) * 64;
    const int q   = lane >> 4;
    const int r16 = lane & 15;

    f32x4 acc[4][4] = {};

    const int trow = tid >> 3;         // 0..31
    const int tcol = (tid & 7) * 8;    // 16B chunk (bf16 elems)

    for (int k0 = 0; k0 < K; k0 += BK) {
        __syncthreads();
        #pragma unroll
        for (int p = 0; p < 4; ++p) {
            int rr = p * 32 + trow;
            *(uint4*)&As[rr * SK + tcol] =
                *(const uint4*)(A + (size_t)(m0 + rr) * lda + k0 + tcol);
            *(uint4*)&Bs[rr * SK + tcol] =
                *(const uint4*)(W + (size_t)(n0 + rr) * ldw + k0 + tcol);
        }
        __syncthreads();
        #pragma unroll
        for (int kk = 0; kk < 2; ++kk) {
            const int ko = kk * 32 + q * 8;
            frag8 af[4], bfr[4];
            #pragma unroll
            for (int i = 0; i < 4; ++i)
                af[i] = *(const frag8*)&As[(wm + i * 16 + r16) * SK + ko];
            #pragma unroll
            for (int j = 0; j < 4; ++j)
                bfr[j] = *(const frag8*)&Bs[(wn + j * 16 + r16) * SK + ko];
            #pragma unroll
            for (int i = 0; i < 4; ++i)
                #pragma unroll
                for (int j = 0; j < 4; ++j)
                    acc[i][j] = __builtin_amdgcn_mfma_f32_16x16x32_bf16(
                        af[i], bfr[j], acc[i][j], 0, 0, 0);
        }
    }

    if (outmode == 0) {
        float* C = (float*)Cv + (size_t)z * sCz;
        #pragma unroll
        for (int i = 0; i < 4; ++i)
            #pragma unroll
            for (int rr = 0; rr < 4; ++rr) {
                int row = m0 + wm + i * 16 + q * 4 + rr;
                float* crow = C + (size_t)row * ldc + n0 + wn + r16;
                #pragma unroll
                for (int j = 0; j < 4; ++j) crow[j * 16] = acc[i][j][rr];
            }
    } else if (outmode == 1) {
        bf16* C = (bf16*)Cv + (size_t)z * sCz;
        #pragma unroll
        for (int i = 0; i < 4; ++i)
            #pragma unroll
            for (int rr = 0; rr < 4; ++rr) {
                int row = m0 + wm + i * 16 + q * 4 + rr;
                bf16* crow = C + (size_t)row * ldc + n0 + wn + r16;
                #pragma unroll
                for (int j = 0; j < 4; ++j) crow[j * 16] = __float2bfloat16(acc[i][j][rr]);
            }
    } else if (outmode == 2) {
        float* C = (float*)Cv + (size_t)z * sCz;
        #pragma unroll
        for (int i = 0; i < 4; ++i)
            #pragma unroll
            for (int rr = 0; rr < 4; ++rr) {
                int row = m0 + wm + i * 16 + q * 4 + rr;
                #pragma unroll
                for (int j = 0; j < 4; ++j) {
                    int col = n0 + wn + j * 16 + r16;
                    if (col < nbound)
                        C[(size_t)row * ldc + col] = sigm(acc[i][j][rr] + bias[col]);
                }
            }
    } else {
        float* C = (float*)Cv + (size_t)z * sCz;
        #pragma unroll
        for (int i = 0; i < 4; ++i)
            #pragma unroll
            for (int rr = 0; rr < 4; ++rr) {
                int row = m0 + wm + i * 16 + q * 4 + rr;
                #pragma unroll
                for (int j = 0; j < 4; ++j) {
                    int col = n0 + wn + j * 16 + r16;
                    if (col < nbound)
                        C[(size_t)row * ldc + col] = acc[i][j][rr];
                }
            }
    }
}

// ---------------- merged hidden-side kernel (async staging + XOR-swizzled LDS) ----------------
// Grid (36, 32): zi = x%6, xt = x/6. XOR swizzle (r10): row R's k-chunk c at pos c^(R&7)
// -> 0 bank conflicts (verified r10). launch_bounds(256,2): r10's (256,4) squeezed the
// unified VGPR+AGPR budget (64 acc-AGPR + ~76 VGPR > 128 cap) -> 26MB scratch spill.
__global__ __launch_bounds__(256, 2)
void gemm_hidden(const bf16* __restrict__ hprev,
                 const bf16* __restrict__ WhFIO,  // [3][768][256]
                 const bf16* __restrict__ WhCb,   // [3][768][768]
                 const bf16* __restrict__ WgH,    // [3][16][768], rows 0..2 = Wh_g[l]
                 const float* __restrict__ big, const float* __restrict__ bhg,  // [9]
                 bf16* __restrict__ hgb,          // [3][4096][768]
                 bf16* __restrict__ auxb,         // [3][4096][768]
                 float* __restrict__ gh)          // [4096][9]
{
    __shared__ __align__(16) short As[BM * 64];
    __shared__ __align__(16) short Bs[BN * 64];
    __shared__ __align__(16) short Bg[16 * 64];

    const int zi = blockIdx.x % 6;
    const int xt = blockIdx.x / 6;
    const bool isaux = zi >= 3;
    const int l = isaux ? zi - 3 : zi;
    const bf16* A = hprev + (isaux ? 0 : l * 256);
    const int K = isaux ? 768 : 256;
    const bf16* W = isaux ? (WhCb + (size_t)l * 768 * 768) : (WhFIO + (size_t)l * 768 * 256);
    const int ldw = isaux ? 768 : 256;
    bf16* C = (isaux ? auxb : hgb) + (size_t)l * 4096 * 768;
    const bool do_g = isaux && (xt == 0);

    const int m0 = blockIdx.y * BM;
    const int n0 = xt * BN;
    const int tid  = threadIdx.x;
    const int lane = tid & 63;
    const int wave = tid >> 6;
    const int wm = (wave >> 1) * 64;
    const int wn = (wave & 1) * 64;
    const int q   = lane >> 4;
    const int r16 = lane & 15;

    f32x4 acc[4][4] = {};
    f32x4 accg[4] = {};

    const int srow = lane >> 3;                      // 0..7 row within 8-row chunk
    const int scolsw = ((lane & 7) ^ srow) * 8;      // XOR-swizzled source chunk
    const bf16* WgL = WgH + (size_t)l * 16 * 768;

    for (int k0 = 0; k0 < K; k0 += BK) {
        __syncthreads();
        #pragma unroll
        for (int p = 0; p < 4; ++p) {
            int rbase = (wave * 4 + p) * 8;
            lds_load16(A + (size_t)(m0 + rbase + srow) * 768 + k0 + scolsw, &As[rbase * 64]);
            lds_load16(W + (size_t)(n0 + rbase + srow) * ldw + k0 + scolsw, &Bs[rbase * 64]);
        }
        if (do_g && wave < 2)
            lds_load16(WgL + (size_t)(wave * 8 + srow) * 768 + k0 + scolsw, &Bg[wave * 8 * 64]);
        __syncthreads();
        #pragma unroll
        for (int kk = 0; kk < 2; ++kk) {
            const int c = kk * 4 + q;   // k-chunk index 0..7
            frag8 af[4], bfr[4];
            #pragma unroll
            for (int i = 0; i < 4; ++i) {
                int R = wm + i * 16 + r16;
                af[i] = *(const frag8*)&As[R * 64 + ((c ^ (R & 7)) << 3)];
            }
            #pragma unroll
            for (int j = 0; j < 4; ++j) {
                int R = wn + j * 16 + r16;
                bfr[j] = *(const frag8*)&Bs[R * 64 + ((c ^ (R & 7)) << 3)];
            }
            #pragma unroll
            for (int i = 0; i < 4; ++i)
                #pragma unroll
                for (int j = 0; j < 4; ++j)
                    acc[i][j] = __builtin_amdgcn_mfma_f32_16x16x32_bf16(
                        af[i], bfr[j], acc[i][j], 0, 0, 0);
            if (do_g) {
                frag8 bg = *(const frag8*)&Bg[r16 * 64 + ((c ^ (r16 & 7)) << 3)];
                #pragma unroll
                for (int i = 0; i < 4; ++i)
                    accg[i] = __builtin_amdgcn_mfma_f32_16x16x32_bf16(
                        af[i], bg, accg[i], 0, 0, 0);
            }
        }
    }

    #pragma unroll
    for (int i = 0; i < 4; ++i)
        #pragma unroll
        for (int rr = 0; rr < 4; ++rr) {
            int row = m0 + wm + i * 16 + q * 4 + rr;
            bf16* crow = C + (size_t)row * 768 + n0 + wn + r16;
            #pragma unroll
            for (int j = 0; j < 4; ++j) crow[j * 16] = __float2bfloat16(acc[i][j][rr]);
        }
    if (do_g && wn == 0 && r16 < 3) {
        float bsum = big[l * 3 + r16] + bhg[l * 3 + r16];
        #pragma unroll
        for (int i = 0; i < 4; ++i)
            #pragma unroll
            for (int rr = 0; rr < 4; ++rr) {
                int row = m0 + wm + i * 16 + q * 4 + rr;
                gh[(size_t)row * 9 + l * 3 + r16] = accg[i][rr] + bsum;
            }
    }
}

// ---------------- fused input-GEMM + gates (layers 1,2) ----------------
// 64m x 128n tile, grid (8, 64) = 512 blocks = 2/CU. Async staging + XOR swizzle.
#define GM 64
struct Stage { short As[GM * 64]; short Bs[BN * 64]; short Bg[16 * 64]; };
union SMemU { Stage s; float ct[GM * 128]; };

__global__ __launch_bounds__(256, 2)
void gemm_gates(const bf16* __restrict__ A, int lda,
                const bf16* __restrict__ Wi, const bf16* __restrict__ Wg,
                const bf16* __restrict__ hg_l,   // [4096][768] bf16
                const bf16* __restrict__ aux_l,  // [4096][768] bf16
                const float* __restrict__ ghc_l, // gh + l*3, stride 9, biases folded
                const float* __restrict__ cprev,
                const float* __restrict__ bif, const float* __restrict__ bhf,
                const float* __restrict__ bii, const float* __restrict__ bhi,
                const float* __restrict__ bio, const float* __restrict__ bho,
                const float* __restrict__ bic, const float* __restrict__ bhc, // [768]
                bf16*  __restrict__ hnew,   // col-slice base, row stride 768
                float* __restrict__ cnew,
                bf16*  __restrict__ featc)  // nullable, row stride 2304
{
    __shared__ __align__(16) SMemU sm;
    __shared__ float gsh[GM * 3];

    const int m0 = blockIdx.y * GM;
    const int n0 = blockIdx.x * BN;
    const int jbase = n0 >> 2;
    const int tid  = threadIdx.x;
    const int lane = tid & 63;
    const int wave = tid >> 6;
    const int wm = (wave >> 1) * 32;   // 2x2 waves, each 32m x 64n
    const int wn = (wave & 1) * 64;
    const int q   = lane >> 4;
    const int r16 = lane & 15;

    f32x4 acc[2][4] = {};
    f32x4 accg[2] = {};

    const int srow = lane >> 3;
    const int scolsw = ((lane & 7) ^ srow) * 8;

    for (int k0 = 0; k0 < 256; k0 += BK) {
        __syncthreads();
        #pragma unroll
        for (int p = 0; p < 2; ++p) {
            int rbase = (wave * 2 + p) * 8;   // A: 64 rows = 8 chunks
            lds_load16(A + (size_t)(m0 + rbase + srow) * lda + k0 + scolsw, &sm.s.As[rbase * 64]);
        }
        #pragma unroll
        for (int p = 0; p < 4; ++p) {
            int rbase = (wave * 4 + p) * 8;   // B: 128 rows = 16 chunks
            lds_load16(Wi + (size_t)(n0 + rbase + srow) * 256 + k0 + scolsw, &sm.s.Bs[rbase * 64]);
        }
        if (wave < 2)
            lds_load16(Wg + (size_t)(wave * 8 + srow) * 256 + k0 + scolsw, &sm.s.Bg[wave * 8 * 64]);
        __syncthreads();
        #pragma unroll
        for (int kk = 0; kk < 2; ++kk) {
            const int c = kk * 4 + q;
            frag8 af[2], bfr[4], bg;
            bg = *(const frag8*)&sm.s.Bg[r16 * 64 + ((c ^ (r16 & 7)) << 3)];
            #pragma unroll
            for (int i = 0; i < 2; ++i) {
                int R = wm + i * 16 + r16;
                af[i] = *(const frag8*)&sm.s.As[R * 64 + ((c ^ (R & 7)) << 3)];
            }
            #pragma unroll
            for (int j = 0; j < 4; ++j) {
                int R = wn + j * 16 + r16;
                bfr[j] = *(const frag8*)&sm.s.Bs[R * 64 + ((c ^ (R & 7)) << 3)];
            }
            #pragma unroll
            for (int i = 0; i < 2; ++i) {
                #pragma unroll
                for (int j = 0; j < 4; ++j)
                    acc[i][j] = __builtin_amdgcn_mfma_f32_16x16x32_bf16(
                        af[i], bfr[j], acc[i][j], 0, 0, 0);
                accg[i] = __builtin_amdgcn_mfma_f32_16x16x32_bf16(
                    af[i], bg, accg[i], 0, 0, 0);
            }
        }
    }

    __syncthreads();   // staging reads done; sm union becomes ct
    // g values: waves with wn==0 (0 and 2) cover rows 0..63
    if (wn == 0 && r16 < 3) {
        #pragma unroll
        for (int i = 0; i < 2; ++i)
            #pragma unroll
            for (int rr = 0; rr < 4; ++rr) {
                int row = wm + i * 16 + q * 4 + rr;
                gsh[row * 3 + r16] = sigm(accg[i][rr] + ghc_l[(size_t)(m0 + row) * 9 + r16]);
            }
    }
    // dump C tile (rotate-swizzled float4 groups)
    #pragma unroll
    for (int i = 0; i < 2; ++i)
        #pragma unroll
        for (int rr = 0; rr < 4; ++rr) {
            int rowl = wm + i * 16 + q * 4 + rr;
            #pragma unroll
            for (int jr = 0; jr < 4; ++jr) {
                int col = wn + jr * 16 + r16;
                sm.ct[rowl * 128 + ((col + 4 * rowl) & 127)] = acc[i][jr][rr];
            }
        }
    __syncthreads();

    const int jj = tid & 31;
    const int r0 = (tid >> 5) * 8;
    const int j  = jbase + jj;
    const float vbif = bif[j], vbhf = bhf[j];
    const float vbii = bii[j], vbhi = bhi[j];
    const float vbio = bio[j], vbho = bho[j];
    const float vbic = bic[j];
    const float vbc0 = bhc[j], vbc1 = bhc[256 + j], vbc2 = bhc[512 + j];

    for (int ri = 0; ri < 8; ++ri) {
        int rowl = r0 + ri;
        size_t b = m0 + rowl;
        float4 pre = *(float4*)&sm.ct[rowl * 128 + ((4 * jj + 4 * rowl) & 127)];
        float g0 = gsh[rowl * 3 + 0];
        float g1 = gsh[rowl * 3 + 1];
        float g2 = gsh[rowl * 3 + 2];
        float hgf = __bfloat162float(hg_l[b * 768 + j]);
        float hgi = __bfloat162float(hg_l[b * 768 + 256 + j]);
        float hgo = __bfloat162float(hg_l[b * 768 + 512 + j]);
        float ax0 = __bfloat162float(aux_l[b * 768 + j]);
        float ax1 = __bfloat162float(aux_l[b * 768 + 256 + j]);
        float ax2 = __bfloat162float(aux_l[b * 768 + 512 + j]);
        float f  = sigm(pre.x + vbif + hgf + vbhf);
        float ii = sigm(pre.y + vbii + hgi + vbhi);
        float o  = sigm(pre.z + vbio + hgo + vbho);
        float av = g0 * (ax0 + vbc0) + g1 * (ax1 + vbc1) + g2 * (ax2 + vbc2);
        float ct = tanhf(pre.w + vbic + av);
        float c  = f * cprev[b * 256 + j] + ii * ct;
        float h  = o * c;
        cnew[b * 256 + j] = c;
        hnew[b * 768 + j] = __float2bfloat16(h);
        if (featc) featc[b * 2304 + j] = __float2bfloat16(h);
    }
}

// ---------------- layer-0 gates from precomputed pre-acts ----------------
// 1024 blocks x 4 rows
__global__ __launch_bounds__(256)
void gates_pre(const bf16* __restrict__ ipre0i, const float* __restrict__ gin0,
               const float* __restrict__ ghc,
               const bf16* __restrict__ hg_l, const bf16* __restrict__ aux_l,
               const float* __restrict__ cprev,
               const float* __restrict__ bif, const float* __restrict__ bhf,
               const float* __restrict__ bii, const float* __restrict__ bhi,
               const float* __restrict__ bio, const float* __restrict__ bho,
               const float* __restrict__ bic, const float* __restrict__ bhc,
               bf16* __restrict__ hnew, float* __restrict__ cnew)
{
    const int j = threadIdx.x;
    const int b0 = blockIdx.x * 4;
    const float vbif = bif[j], vbhf = bhf[j];
    const float vbii = bii[j], vbhi = bhi[j];
    const float vbio = bio[j], vbho = bho[j];
    const float vbic = bic[j];
    const float vbc0 = bhc[j], vbc1 = bhc[256 + j], vbc2 = bhc[512 + j];

    #pragma unroll
    for (int r = 0; r < 4; ++r) {
        const size_t b = b0 + r;
        const bf16* ip4 = ipre0i + b * 1024 + 4 * j;
        float pf = __bfloat162float(ip4[0]);
        float pi = __bfloat162float(ip4[1]);
        float po = __bfloat162float(ip4[2]);
        float pc = __bfloat162float(ip4[3]);
        float g0 = sigm(gin0[b * 3 + 0] + ghc[b * 9 + 0]);
        float g1 = sigm(gin0[b * 3 + 1] + ghc[b * 9 + 1]);
        float g2 = sigm(gin0[b * 3 + 2] + ghc[b * 9 + 2]);
        float hgf = __bfloat162float(hg_l[b * 768 + j]);
        float hgi = __bfloat162float(hg_l[b * 768 + 256 + j]);
        float hgo = __bfloat162float(hg_l[b * 768 + 512 + j]);
        float ax0 = __bfloat162float(aux_l[b * 768 + j]);
        float ax1 = __bfloat162float(aux_l[b * 768 + 256 + j]);
        float ax2 = __bfloat162float(aux_l[b * 768 + 512 + j]);
        float f  = sigm(pf + vbif + hgf + vbhf);
        float ii = sigm(pi + vbii + hgi + vbhi);
        float o  = sigm(po + vbio + hgo + vbho);
        float av = g0 * (ax0 + vbc0) + g1 * (ax1 + vbc1) + g2 * (ax2 + vbc2);
        float ct = tanhf(pc + vbic + av);
        float c  = f * cprev[b * 256 + j] + ii * ct;
        float h  = o * c;
        cnew[b * 256 + j] = c;
        hnew[b * 768 + j] = __float2bfloat16(h);
    }
}

// gin0[b][s] = xb[b,:] . Wi_g[0][s][:]  (no bias; constant over t)
__global__ __launch_bounds__(256)
void gin0_kernel(const bf16* __restrict__ xb, const float* __restrict__ Wig,
                 float* __restrict__ gout)
{
    const int wave = threadIdx.x >> 6, lane = threadIdx.x & 63;
    for (int rep = 0; rep < 4; ++rep) {
        size_t b = (size_t)blockIdx.x * 16 + wave * 4 + rep;
        float hv[4];
        #pragma unroll
        for (int m = 0; m < 4; ++m)
            hv[m] = __bfloat162float(xb[b * 256 + m * 64 + lane]);
        float p[3];
        #pragma unroll
        for (int s = 0; s < 3; ++s) {
            float t = 0.f;
            const float* w = Wig + (size_t)s * 256;
            #pragma unroll
            for (int m = 0; m < 4; ++m) t += hv[m] * w[m * 64 + lane];
            p[s] = t;
        }
        #pragma unroll
        for (int off = 32; off; off >>= 1)
            #pragma unroll
            for (int s = 0; s < 3; ++s) p[s] += __shfl_down(p[s], off);
        if (lane == 0) {
            #pragma unroll
            for (int s = 0; s < 3; ++s) gout[b * 3 + s] = p[s];
        }
    }
}

// out[b][n] = sigm(bias[n] + sum_z part[z][b][n]), n<44
__global__ __launch_bounds__(256)
void final_reduce(const float* __restrict__ part, const float* __restrict__ bl,
                  float* __restrict__ out)
{
    int idx = blockIdx.x * 256 + threadIdx.x;
    if (idx >= 4096 * 44) return;
    int b = idx / 44, n = idx - b * 44;
    float s = bl[n];
    #pragma unroll
    for (int z = 0; z < 12; ++z) s += part[(size_t)z * 4096 * 64 + (size_t)b * 64 + n];
    out[idx] = sigm(s);
}

// ---------------- prep kernels ----------------
__global__ void build_wicati(const float* __restrict__ Wf, const float* __restrict__ Wi,
                             const float* __restrict__ Wo, const float* __restrict__ Wc,
                             bf16* __restrict__ out)
{
    int idx = blockIdx.x * 256 + threadIdx.x;  // 3*1024*256
    int k = idx & 255, n = (idx >> 8) & 1023, l = idx >> 18;
    int j = n >> 2, g = n & 3;
    const float* src = (g == 0) ? Wf : (g == 1) ? Wi : (g == 2) ? Wo : Wc;
    out[idx] = __float2bfloat16(src[l * 65536 + j * 256 + k]);
}

__global__ void build_whfio(const float* __restrict__ Wf, const float* __restrict__ Wi,
                            const float* __restrict__ Wo, bf16* __restrict__ out)
{
    int idx = blockIdx.x * 256 + threadIdx.x;  // 3*768*256
    int k = idx & 255, n = (idx >> 8) % 768, l = idx / 196608;
    const float* src = (n < 256) ? Wf : (n < 512) ? Wi : Wo;
    out[idx] = __float2bfloat16(src[l * 65536 + (n & 255) * 256 + k]);
}

__global__ void build_wg(const float* __restrict__ Wig, bf16* __restrict__ out)
{
    int idx = blockIdx.x * 256 + threadIdx.x;  // 3*16*256
    int k = idx & 255, r = (idx >> 8) & 15, l = idx >> 12;
    out[idx] = (r < 3) ? __float2bfloat16(Wig[l * 768 + r * 256 + k]) : __float2bfloat16(0.f);
}

// WgH [3][16][768]: rows 0..2 = Wh_g[l], rest zero
__global__ void build_wgh(const float* __restrict__ Whg, bf16* __restrict__ out)
{
    int idx = blockIdx.x * 256 + threadIdx.x;  // 3*16*768
    int k = idx % 768, r = (idx / 768) & 15, l = idx / (16 * 768);
    out[idx] = (r < 3) ? __float2bfloat16(Whg[(l * 3 + r) * 768 + k]) : __float2bfloat16(0.f);
}

__global__ void build_wlast(const float* __restrict__ Wl, bf16* __restrict__ out)
{
    int idx = blockIdx.x * 256 + threadIdx.x;  // 128*2304
    int k = idx % 2304, n = idx / 2304;
    out[idx] = (n < 44) ? __float2bfloat16(Wl[n * 2304 + k]) : __float2bfloat16(0.f);
}

__global__ void convert_f2b(const float* __restrict__ in, bf16* __restrict__ out, int n)
{
    int idx = blockIdx.x * 256 + threadIdx.x;
    if (idx < n) out[idx] = __float2bfloat16(in[idx]);
}

__global__ void init_state(const float* __restrict__ hidden0, const float* __restrict__ current0,
                           bf16* __restrict__ hcat, float* __restrict__ c0)
{
    int idx = blockIdx.x * 256 + threadIdx.x;  // 3*4096*256
    int j = idx & 255, b = (idx >> 8) & 4095, l = idx >> 20;
    hcat[(size_t)b * 768 + l * 256 + j] = __float2bfloat16(hidden0[idx]);
    c0[idx] = current0[idx];
}

extern "C" void kernel_launch(void* const* d_in, const int* in_sizes, int n_in,
                              void* d_out, int out_size, void* d_ws, size_t ws_size,
                              hipStream_t stream)
{
    (void)in_sizes; (void)n_in; (void)out_size; (void)ws_size;
    const float* x        = (const float*)d_in[0];
    const float* hidden0  = (const float*)d_in[1];
    const float* current0 = (const float*)d_in[2];
    const float* Wi_f = (const float*)d_in[3];  const float* bi_f = (const float*)d_in[4];
    const float* Wi_i = (const float*)d_in[5];  const float* bi_i = (const float*)d_in[6];
    const float* Wi_o = (const float*)d_in[7];  const float* bi_o = (const float*)d_in[8];
    const float* Wi_c = (const float*)d_in[9];  const float* bi_c = (const float*)d_in[10];
    const float* Wi_g = (const float*)d_in[11]; const float* bi_g = (const float*)d_in[12];
    const float* Wh_f = (const float*)d_in[13]; const float* bh_f = (const float*)d_in[14];
    const float* Wh_i = (const float*)d_in[15]; const float* bh_i = (const float*)d_in[16];
    const float* Wh_o = (const float*)d_in[17]; const float* bh_o = (const float*)d_in[18];
    const float* Wh_g = (const float*)d_in[19]; const float* bh_g = (const float*)d_in[20];
    const float* Wh_c = (const float*)d_in[21]; const float* bh_c = (const float*)d_in[22];
    const float* W_last = (const float*)d_in[23]; const float* b_last = (const float*)d_in[24];

    char* p = (char*)d_ws;
    bf16* WiCatI = (bf16*)p; p += (size_t)3 * 1024 * 256 * 2;
    bf16* WhFIO  = (bf16*)p; p += (size_t)3 * 768 * 256 * 2;
    bf16* WhCb   = (bf16*)p; p += (size_t)3 * 768 * 768 * 2;
    bf16* Wgb    = (bf16*)p; p += (size_t)3 * 16 * 256 * 2;
    bf16* WgH    = (bf16*)p; p += (size_t)3 * 16 * 768 * 2;
    bf16* Wlb    = (bf16*)p; p += (size_t)128 * 2304 * 2;
    bf16* xb     = (bf16*)p; p += (size_t)4096 * 256 * 2;
    bf16* ipre0i = (bf16*)p; p += (size_t)4096 * 1024 * 2;
    float* gin0  = (float*)p; p += (size_t)4096 * 3 * 4;
    bf16* hb0    = (bf16*)p; p += (size_t)4096 * 768 * 2;
    bf16* hb1    = (bf16*)p; p += (size_t)4096 * 768 * 2;
    float* cb0   = (float*)p; p += (size_t)3 * 4096 * 256 * 4;
    float* cb1   = (float*)p; p += (size_t)3 * 4096 * 256 * 4;
    bf16* hgb    = (bf16*)p; p += (size_t)3 * 4096 * 768 * 2;
    bf16* auxb   = (bf16*)p; p += (size_t)3 * 4096 * 768 * 2;
    float* gh    = (float*)p; p += (size_t)4096 * 9 * 4;
    bf16* feat   = (bf16*)p; p += (size_t)4096 * 2304 * 2;
    float* partf = (float*)p; p += (size_t)12 * 4096 * 64 * 4;

    build_wicati<<<3072, 256, 0, stream>>>(Wi_f, Wi_i, Wi_o, Wi_c, WiCatI);
    build_whfio<<<2304, 256, 0, stream>>>(Wh_f, Wh_i, Wh_o, WhFIO);
    convert_f2b<<<(3 * 768 * 768 + 255) / 256, 256, 0, stream>>>(Wh_c, WhCb, 3 * 768 * 768);
    build_wg<<<48, 256, 0, stream>>>(Wi_g, Wgb);
    build_wgh<<<144, 256, 0, stream>>>(Wh_g, WgH);
    build_wlast<<<1152, 256, 0, stream>>>(W_last, Wlb);
    convert_f2b<<<4096, 256, 0, stream>>>(x, xb, 4096 * 256);
    init_state<<<12288, 256, 0, stream>>>(hidden0, current0, hb0, cb0);

    // hoisted layer-0 input-side work (x constant across t)
    gemm_bt<<<dim3(8, 32, 1), 256, 0, stream>>>(xb, 256, 0, WiCatI, 256, 0,
                                                ipre0i, 1024, 0, 256, 1, nullptr, 0);
    gin0_kernel<<<256, 256, 0, stream>>>(xb, Wi_g, gin0);

    for (int t = 0; t < 10; ++t) {
        bf16* hprev = (t & 1) ? hb1 : hb0;
        bf16* hnew  = (t & 1) ? hb0 : hb1;
        float* cprev = (t & 1) ? cb1 : cb0;
        float* cnew  = (t & 1) ? cb0 : cb1;

        gemm_hidden<<<dim3(36, 32), 256, 0, stream>>>(
            hprev, WhFIO, WhCb, WgH, bi_g, bh_g, hgb, auxb, gh);

        gates_pre<<<1024, 256, 0, stream>>>(
            ipre0i, gin0, gh,
            hgb, auxb, cprev,
            bi_f, bh_f, bi_i, bh_i, bi_o, bh_o, bi_c, bh_c,
            hnew, cnew);

        for (int l = 1; l < 3; ++l) {
            gemm_gates<<<dim3(8, 64), 256, 0, stream>>>(
                (const bf16*)(hnew + (l - 1) * 256), 768,
                WiCatI + (size_t)l * 1024 * 256,
                Wgb + (size_t)l * 16 * 256,
                hgb + (size_t)l * 4096 * 768,
                auxb + (size_t)l * 4096 * 768,
                gh + l * 3,
                cprev + (size_t)l * 4096 * 256,
                bi_f + l * 256, bh_f + l * 256,
                bi_i + l * 256, bh_i + l * 256,
                bi_o + l * 256, bh_o + l * 256,
                bi_c + l * 256, bh_c + l * 768,
                hnew + l * 256,
                cnew + (size_t)l * 4096 * 256,
                (l == 2 && t < 9) ? (feat + (size_t)t * 256) : (bf16*)nullptr);
        }
    }

    // final: K-split feat[4096,2304] @ Wlb[128,2304]^T into 12 partials of K=192
    gemm_bt<<<dim3(1, 32, 12), 256, 0, stream>>>(
        feat, 2304, 192, Wlb, 2304, 192,
        partf, 64, (long long)4096 * 64, 192, 3, nullptr, 64);
    final_reduce<<<704, 256, 0, stream>>>(partf, b_last, (float*)d_out);
}

// Round 12
// 824.010 us; speedup vs baseline: 1.4424x; 1.0355x over previous
//
#include <hip/hip_runtime.h>
#include <hip/hip_bf16.h>

typedef __hip_bfloat16 bf16;
typedef __attribute__((ext_vector_type(8))) short frag8;   // 8 bf16 = 4 VGPRs
typedef __attribute__((ext_vector_type(4))) float f32x4;

#define BM 128
#define BN 128
#define BK 64
#define SK 72   // padded LDS stride for VGPR-staged kernels

__device__ __forceinline__ float sigm(float x) { return 1.f / (1.f + __expf(-x)); }

// async global->LDS, 16B/lane; lds base wave-uniform, lane scatters at +lane*16
__device__ __forceinline__ void lds_load16(const bf16* g, short* l) {
    __builtin_amdgcn_global_load_lds(
        (const __attribute__((address_space(1))) void*)g,
        (__attribute__((address_space(3))) void*)l, 16, 0, 0);
}

// C[m,n] = sum_k A[m,k] * W[n,k]; 128x128 tile, padded in-loop VGPR staging.
// outmode: 0 fp32, 1 bf16, 2 sigmoid(acc+bias[n]) fp32 n<nbound, 3 raw fp32 n<nbound.
__global__ __launch_bounds__(256, 2)
void gemm_bt(const bf16* __restrict__ A, int lda, long long sAz,
             const bf16* __restrict__ W, int ldw, long long sWz,
             void* __restrict__ Cv, int ldc, long long sCz, int K,
             int outmode, const float* __restrict__ bias, int nbound)
{
    __shared__ short As[BM * SK];
    __shared__ short Bs[BN * SK];
    const int z = blockIdx.z;
    A += (size_t)z * sAz;
    W += (size_t)z * sWz;
    const int m0 = blockIdx.y * BM;
    const int n0 = blockIdx.x * BN;
    const int tid  = threadIdx.x;
    const int lane = tid & 63;
    const int wave = tid >> 6;
    const int wm = (wave >> 1) * 64;
    const int wn = (wave & 1) * 64;
    const int q   = lane >> 4;
    const int r16 = lane & 15;

    f32x4 acc[4][4] = {};

    const int trow = tid >> 3;         // 0..31
    const int tcol = (tid & 7) * 8;    // 16B chunk (bf16 elems)

    for (int k0 = 0; k0 < K; k0 += BK) {
        __syncthreads();
        #pragma unroll
        for (int p = 0; p < 4; ++p) {
            int rr = p * 32 + trow;
            *(uint4*)&As[rr * SK + tcol] =
                *(const uint4*)(A + (size_t)(m0 + rr) * lda + k0 + tcol);
            *(uint4*)&Bs[rr * SK + tcol] =
                *(const uint4*)(W + (size_t)(n0 + rr) * ldw + k0 + tcol);
        }
        __syncthreads();
        #pragma unroll
        for (int kk = 0; kk < 2; ++kk) {
            const int ko = kk * 32 + q * 8;
            frag8 af[4], bfr[4];
            #pragma unroll
            for (int i = 0; i < 4; ++i)
                af[i] = *(const frag8*)&As[(wm + i * 16 + r16) * SK + ko];
            #pragma unroll
            for (int j = 0; j < 4; ++j)
                bfr[j] = *(const frag8*)&Bs[(wn + j * 16 + r16) * SK + ko];
            #pragma unroll
            for (int i = 0; i < 4; ++i)
                #pragma unroll
                for (int j = 0; j < 4; ++j)
                    acc[i][j] = __builtin_amdgcn_mfma_f32_16x16x32_bf16(
                        af[i], bfr[j], acc[i][j], 0, 0, 0);
        }
    }

    if (outmode == 0) {
        float* C = (float*)Cv + (size_t)z * sCz;
        #pragma unroll
        for (int i = 0; i < 4; ++i)
            #pragma unroll
            for (int rr = 0; rr < 4; ++rr) {
                int row = m0 + wm + i * 16 + q * 4 + rr;
                float* crow = C + (size_t)row * ldc + n0 + wn + r16;
                #pragma unroll
                for (int j = 0; j < 4; ++j) crow[j * 16] = acc[i][j][rr];
            }
    } else if (outmode == 1) {
        bf16* C = (bf16*)Cv + (size_t)z * sCz;
        #pragma unroll
        for (int i = 0; i < 4; ++i)
            #pragma unroll
            for (int rr = 0; rr < 4; ++rr) {
                int row = m0 + wm + i * 16 + q * 4 + rr;
                bf16* crow = C + (size_t)row * ldc + n0 + wn + r16;
                #pragma unroll
                for (int j = 0; j < 4; ++j) crow[j * 16] = __float2bfloat16(acc[i][j][rr]);
            }
    } else if (outmode == 2) {
        float* C = (float*)Cv + (size_t)z * sCz;
        #pragma unroll
        for (int i = 0; i < 4; ++i)
            #pragma unroll
            for (int rr = 0; rr < 4; ++rr) {
                int row = m0 + wm + i * 16 + q * 4 + rr;
                #pragma unroll
                for (int j = 0; j < 4; ++j) {
                    int col = n0 + wn + j * 16 + r16;
                    if (col < nbound)
                        C[(size_t)row * ldc + col] = sigm(acc[i][j][rr] + bias[col]);
                }
            }
    } else {
        float* C = (float*)Cv + (size_t)z * sCz;
        #pragma unroll
        for (int i = 0; i < 4; ++i)
            #pragma unroll
            for (int rr = 0; rr < 4; ++rr) {
                int row = m0 + wm + i * 16 + q * 4 + rr;
                #pragma unroll
                for (int j = 0; j < 4; ++j) {
                    int col = n0 + wn + j * 16 + r16;
                    if (col < nbound)
                        C[(size_t)row * ldc + col] = acc[i][j][rr];
                }
            }
    }
}

// ---------------- merged hidden-side kernel (async staging + XOR-swizzled LDS) ----------------
// Grid (36, 32): zi = x%6, xt = x/6. XOR swizzle: 0 bank conflicts (verified r10/r11).
// launch_bounds(256,3): unified-file math = 76 VGPR + 80 AGPR = 156 <= 512/3 = 170 cap
// (r10's (256,4) failed because the cap there is 128). 3 blocks/CU hides barrier drain.
__global__ __launch_bounds__(256, 3)
void gemm_hidden(const bf16* __restrict__ hprev,
                 const bf16* __restrict__ WhFIO,  // [3][768][256]
                 const bf16* __restrict__ WhCb,   // [3][768][768]
                 const bf16* __restrict__ WgH,    // [3][16][768], rows 0..2 = Wh_g[l]
                 const float* __restrict__ big, const float* __restrict__ bhg,  // [9]
                 bf16* __restrict__ hgb,          // [3][4096][768]
                 bf16* __restrict__ auxb,         // [3][4096][768]
                 float* __restrict__ gh)          // [4096][9]
{
    __shared__ __align__(16) short As[BM * 64];
    __shared__ __align__(16) short Bs[BN * 64];
    __shared__ __align__(16) short Bg[16 * 64];

    const int zi = blockIdx.x % 6;
    const int xt = blockIdx.x / 6;
    const bool isaux = zi >= 3;
    const int l = isaux ? zi - 3 : zi;
    const bf16* A = hprev + (isaux ? 0 : l * 256);
    const int K = isaux ? 768 : 256;
    const bf16* W = isaux ? (WhCb + (size_t)l * 768 * 768) : (WhFIO + (size_t)l * 768 * 256);
    const int ldw = isaux ? 768 : 256;
    bf16* C = (isaux ? auxb : hgb) + (size_t)l * 4096 * 768;
    const bool do_g = isaux && (xt == 0);

    const int m0 = blockIdx.y * BM;
    const int n0 = xt * BN;
    const int tid  = threadIdx.x;
    const int lane = tid & 63;
    const int wave = tid >> 6;
    const int wm = (wave >> 1) * 64;
    const int wn = (wave & 1) * 64;
    const int q   = lane >> 4;
    const int r16 = lane & 15;

    f32x4 acc[4][4] = {};
    f32x4 accg[4] = {};

    const int srow = lane >> 3;                      // 0..7 row within 8-row chunk
    const int scolsw = ((lane & 7) ^ srow) * 8;      // XOR-swizzled source chunk
    const bf16* WgL = WgH + (size_t)l * 16 * 768;

    for (int k0 = 0; k0 < K; k0 += BK) {
        __syncthreads();
        #pragma unroll
        for (int p = 0; p < 4; ++p) {
            int rbase = (wave * 4 + p) * 8;
            lds_load16(A + (size_t)(m0 + rbase + srow) * 768 + k0 + scolsw, &As[rbase * 64]);
            lds_load16(W + (size_t)(n0 + rbase + srow) * ldw + k0 + scolsw, &Bs[rbase * 64]);
        }
        if (do_g && wave < 2)
            lds_load16(WgL + (size_t)(wave * 8 + srow) * 768 + k0 + scolsw, &Bg[wave * 8 * 64]);
        __syncthreads();
        #pragma unroll
        for (int kk = 0; kk < 2; ++kk) {
            const int c = kk * 4 + q;   // k-chunk index 0..7
            frag8 af[4], bfr[4];
            #pragma unroll
            for (int i = 0; i < 4; ++i) {
                int R = wm + i * 16 + r16;
                af[i] = *(const frag8*)&As[R * 64 + ((c ^ (R & 7)) << 3)];
            }
            #pragma unroll
            for (int j = 0; j < 4; ++j) {
                int R = wn + j * 16 + r16;
                bfr[j] = *(const frag8*)&Bs[R * 64 + ((c ^ (R & 7)) << 3)];
            }
            #pragma unroll
            for (int i = 0; i < 4; ++i)
                #pragma unroll
                for (int j = 0; j < 4; ++j)
                    acc[i][j] = __builtin_amdgcn_mfma_f32_16x16x32_bf16(
                        af[i], bfr[j], acc[i][j], 0, 0, 0);
            if (do_g) {
                frag8 bg = *(const frag8*)&Bg[r16 * 64 + ((c ^ (r16 & 7)) << 3)];
                #pragma unroll
                for (int i = 0; i < 4; ++i)
                    accg[i] = __builtin_amdgcn_mfma_f32_16x16x32_bf16(
                        af[i], bg, accg[i], 0, 0, 0);
            }
        }
    }

    #pragma unroll
    for (int i = 0; i < 4; ++i)
        #pragma unroll
        for (int rr = 0; rr < 4; ++rr) {
            int row = m0 + wm + i * 16 + q * 4 + rr;
            bf16* crow = C + (size_t)row * 768 + n0 + wn + r16;
            #pragma unroll
            for (int j = 0; j < 4; ++j) crow[j * 16] = __float2bfloat16(acc[i][j][rr]);
        }
    if (do_g && wn == 0 && r16 < 3) {
        float bsum = big[l * 3 + r16] + bhg[l * 3 + r16];
        #pragma unroll
        for (int i = 0; i < 4; ++i)
            #pragma unroll
            for (int rr = 0; rr < 4; ++rr) {
                int row = m0 + wm + i * 16 + q * 4 + rr;
                gh[(size_t)row * 9 + l * 3 + r16] = accg[i][rr] + bsum;
            }
    }
}

// ---------------- fused input-GEMM + gates (layers 1,2) ----------------
// 64m x 128n tile, grid (8, 64) = 512 blocks = 2/CU. Async staging + XOR swizzle.
#define GM 64
struct Stage { short As[GM * 64]; short Bs[BN * 64]; short Bg[16 * 64]; };
union SMemU { Stage s; float ct[GM * 128]; };

__global__ __launch_bounds__(256, 2)
void gemm_gates(const bf16* __restrict__ A, int lda,
                const bf16* __restrict__ Wi, const bf16* __restrict__ Wg,
                const bf16* __restrict__ hg_l,   // [4096][768] bf16
                const bf16* __restrict__ aux_l,  // [4096][768] bf16
                const float* __restrict__ ghc_l, // gh + l*3, stride 9, biases folded
                const float* __restrict__ cprev,
                const float* __restrict__ bif, const float* __restrict__ bhf,
                const float* __restrict__ bii, const float* __restrict__ bhi,
                const float* __restrict__ bio, const float* __restrict__ bho,
                const float* __restrict__ bic, const float* __restrict__ bhc, // [768]
                bf16*  __restrict__ hnew,   // col-slice base, row stride 768
                float* __restrict__ cnew,
                bf16*  __restrict__ featc)  // nullable, row stride 2304
{
    __shared__ __align__(16) SMemU sm;
    __shared__ float gsh[GM * 3];

    const int m0 = blockIdx.y * GM;
    const int n0 = blockIdx.x * BN;
    const int jbase = n0 >> 2;
    const int tid  = threadIdx.x;
    const int lane = tid & 63;
    const int wave = tid >> 6;
    const int wm = (wave >> 1) * 32;   // 2x2 waves, each 32m x 64n
    const int wn = (wave & 1) * 64;
    const int q   = lane >> 4;
    const int r16 = lane & 15;

    f32x4 acc[2][4] = {};
    f32x4 accg[2] = {};

    const int srow = lane >> 3;
    const int scolsw = ((lane & 7) ^ srow) * 8;

    for (int k0 = 0; k0 < 256; k0 += BK) {
        __syncthreads();
        #pragma unroll
        for (int p = 0; p < 2; ++p) {
            int rbase = (wave * 2 + p) * 8;   // A: 64 rows = 8 chunks
            lds_load16(A + (size_t)(m0 + rbase + srow) * lda + k0 + scolsw, &sm.s.As[rbase * 64]);
        }
        #pragma unroll
        for (int p = 0; p < 4; ++p) {
            int rbase = (wave * 4 + p) * 8;   // B: 128 rows = 16 chunks
            lds_load16(Wi + (size_t)(n0 + rbase + srow) * 256 + k0 + scolsw, &sm.s.Bs[rbase * 64]);
        }
        if (wave < 2)
            lds_load16(Wg + (size_t)(wave * 8 + srow) * 256 + k0 + scolsw, &sm.s.Bg[wave * 8 * 64]);
        __syncthreads();
        #pragma unroll
        for (int kk = 0; kk < 2; ++kk) {
            const int c = kk * 4 + q;
            frag8 af[2], bfr[4], bg;
            bg = *(const frag8*)&sm.s.Bg[r16 * 64 + ((c ^ (r16 & 7)) << 3)];
            #pragma unroll
            for (int i = 0; i < 2; ++i) {
                int R = wm + i * 16 + r16;
                af[i] = *(const frag8*)&sm.s.As[R * 64 + ((c ^ (R & 7)) << 3)];
            }
            #pragma unroll
            for (int j = 0; j < 4; ++j) {
                int R = wn + j * 16 + r16;
                bfr[j] = *(const frag8*)&sm.s.Bs[R * 64 + ((c ^ (R & 7)) << 3)];
            }
            #pragma unroll
            for (int i = 0; i < 2; ++i) {
                #pragma unroll
                for (int j = 0; j < 4; ++j)
                    acc[i][j] = __builtin_amdgcn_mfma_f32_16x16x32_bf16(
                        af[i], bfr[j], acc[i][j], 0, 0, 0);
                accg[i] = __builtin_amdgcn_mfma_f32_16x16x32_bf16(
                    af[i], bg, accg[i], 0, 0, 0);
            }
        }
    }

    __syncthreads();   // staging reads done; sm union becomes ct
    // g values: waves with wn==0 (0 and 2) cover rows 0..63
    if (wn == 0 && r16 < 3) {
        #pragma unroll
        for (int i = 0; i < 2; ++i)
            #pragma unroll
            for (int rr = 0; rr < 4; ++rr) {
                int row = wm + i * 16 + q * 4 + rr;
                gsh[row * 3 + r16] = sigm(accg[i][rr] + ghc_l[(size_t)(m0 + row) * 9 + r16]);
            }
    }
    // dump C tile (rotate-swizzled float4 groups)
    #pragma unroll
    for (int i = 0; i < 2; ++i)
        #pragma unroll
        for (int rr = 0; rr < 4; ++rr) {
            int rowl = wm + i * 16 + q * 4 + rr;
            #pragma unroll
            for (int jr = 0; jr < 4; ++jr) {
                int col = wn + jr * 16 + r16;
                sm.ct[rowl * 128 + ((col + 4 * rowl) & 127)] = acc[i][jr][rr];
            }
        }
    __syncthreads();

    const int jj = tid & 31;
    const int r0 = (tid >> 5) * 8;
    const int j  = jbase + jj;
    const float vbif = bif[j], vbhf = bhf[j];
    const float vbii = bii[j], vbhi = bhi[j];
    const float vbio = bio[j], vbho = bho[j];
    const float vbic = bic[j];
    const float vbc0 = bhc[j], vbc1 = bhc[256 + j], vbc2 = bhc[512 + j];

    for (int ri = 0; ri < 8; ++ri) {
        int rowl = r0 + ri;
        size_t b = m0 + rowl;
        float4 pre = *(float4*)&sm.ct[rowl * 128 + ((4 * jj + 4 * rowl) & 127)];
        float g0 = gsh[rowl * 3 + 0];
        float g1 = gsh[rowl * 3 + 1];
        float g2 = gsh[rowl * 3 + 2];
        float hgf = __bfloat162float(hg_l[b * 768 + j]);
        float hgi = __bfloat162float(hg_l[b * 768 + 256 + j]);
        float hgo = __bfloat162float(hg_l[b * 768 + 512 + j]);
        float ax0 = __bfloat162float(aux_l[b * 768 + j]);
        float ax1 = __bfloat162float(aux_l[b * 768 + 256 + j]);
        float ax2 = __bfloat162float(aux_l[b * 768 + 512 + j]);
        float f  = sigm(pre.x + vbif + hgf + vbhf);
        float ii = sigm(pre.y + vbii + hgi + vbhi);
        float o  = sigm(pre.z + vbio + hgo + vbho);
        float av = g0 * (ax0 + vbc0) + g1 * (ax1 + vbc1) + g2 * (ax2 + vbc2);
        float ct = tanhf(pre.w + vbic + av);
        float c  = f * cprev[b * 256 + j] + ii * ct;
        float h  = o * c;
        cnew[b * 256 + j] = c;
        hnew[b * 768 + j] = __float2bfloat16(h);
        if (featc) featc[b * 2304 + j] = __float2bfloat16(h);
    }
}

// ---------------- layer-0 gates from precomputed pre-acts ----------------
// 1024 blocks x 4 rows
__global__ __launch_bounds__(256)
void gates_pre(const bf16* __restrict__ ipre0i, const float* __restrict__ gin0,
               const float* __restrict__ ghc,
               const bf16* __restrict__ hg_l, const bf16* __restrict__ aux_l,
               const float* __restrict__ cprev,
               const float* __restrict__ bif, const float* __restrict__ bhf,
               const float* __restrict__ bii, const float* __restrict__ bhi,
               const float* __restrict__ bio, const float* __restrict__ bho,
               const float* __restrict__ bic, const float* __restrict__ bhc,
               bf16* __restrict__ hnew, float* __restrict__ cnew)
{
    const int j = threadIdx.x;
    const int b0 = blockIdx.x * 4;
    const float vbif = bif[j], vbhf = bhf[j];
    const float vbii = bii[j], vbhi = bhi[j];
    const float vbio = bio[j], vbho = bho[j];
    const float vbic = bic[j];
    const float vbc0 = bhc[j], vbc1 = bhc[256 + j], vbc2 = bhc[512 + j];

    #pragma unroll
    for (int r = 0; r < 4; ++r) {
        const size_t b = b0 + r;
        const bf16* ip4 = ipre0i + b * 1024 + 4 * j;
        float pf = __bfloat162float(ip4[0]);
        float pi = __bfloat162float(ip4[1]);
        float po = __bfloat162float(ip4[2]);
        float pc = __bfloat162float(ip4[3]);
        float g0 = sigm(gin0[b * 3 + 0] + ghc[b * 9 + 0]);
        float g1 = sigm(gin0[b * 3 + 1] + ghc[b * 9 + 1]);
        float g2 = sigm(gin0[b * 3 + 2] + ghc[b * 9 + 2]);
        float hgf = __bfloat162float(hg_l[b * 768 + j]);
        float hgi = __bfloat162float(hg_l[b * 768 + 256 + j]);
        float hgo = __bfloat162float(hg_l[b * 768 + 512 + j]);
        float ax0 = __bfloat162float(aux_l[b * 768 + j]);
        float ax1 = __bfloat162float(aux_l[b * 768 + 256 + j]);
        float ax2 = __bfloat162float(aux_l[b * 768 + 512 + j]);
        float f  = sigm(pf + vbif + hgf + vbhf);
        float ii = sigm(pi + vbii + hgi + vbhi);
        float o  = sigm(po + vbio + hgo + vbho);
        float av = g0 * (ax0 + vbc0) + g1 * (ax1 + vbc1) + g2 * (ax2 + vbc2);
        float ct = tanhf(pc + vbic + av);
        float c  = f * cprev[b * 256 + j] + ii * ct;
        float h  = o * c;
        cnew[b * 256 + j] = c;
        hnew[b * 768 + j] = __float2bfloat16(h);
    }
}

// gin0[b][s] = xb[b,:] . Wi_g[0][s][:]  (no bias; constant over t)
__global__ __launch_bounds__(256)
void gin0_kernel(const bf16* __restrict__ xb, const float* __restrict__ Wig,
                 float* __restrict__ gout)
{
    const int wave = threadIdx.x >> 6, lane = threadIdx.x & 63;
    for (int rep = 0; rep < 4; ++rep) {
        size_t b = (size_t)blockIdx.x * 16 + wave * 4 + rep;
        float hv[4];
        #pragma unroll
        for (int m = 0; m < 4; ++m)
            hv[m] = __bfloat162float(xb[b * 256 + m * 64 + lane]);
        float p[3];
        #pragma unroll
        for (int s = 0; s < 3; ++s) {
            float t = 0.f;
            const float* w = Wig + (size_t)s * 256;
            #pragma unroll
            for (int m = 0; m < 4; ++m) t += hv[m] * w[m * 64 + lane];
            p[s] = t;
        }
        #pragma unroll
        for (int off = 32; off; off >>= 1)
            #pragma unroll
            for (int s = 0; s < 3; ++s) p[s] += __shfl_down(p[s], off);
        if (lane == 0) {
            #pragma unroll
            for (int s = 0; s < 3; ++s) gout[b * 3 + s] = p[s];
        }
    }
}

// out[b][n] = sigm(bias[n] + sum_z part[z][b][n]), n<44
__global__ __launch_bounds__(256)
void final_reduce(const float* __restrict__ part, const float* __restrict__ bl,
                  float* __restrict__ out)
{
    int idx = blockIdx.x * 256 + threadIdx.x;
    if (idx >= 4096 * 44) return;
    int b = idx / 44, n = idx - b * 44;
    float s = bl[n];
    #pragma unroll
    for (int z = 0; z < 12; ++z) s += part[(size_t)z * 4096 * 64 + (size_t)b * 64 + n];
    out[idx] = sigm(s);
}

// ---------------- single merged prep kernel (replaces 8 launches) ----------------
// Segment sizes (elements):
//   0: WiCatI 786432   1: WhFIO 589824   2: WhCb 1769472   3: Wgb 12288
//   4: WgH 36864       5: Wlb 294912     6: xb 1048576     7: state 3145728
__global__ __launch_bounds__(256)
void prep_all(const float* __restrict__ Wi_f, const float* __restrict__ Wi_i,
              const float* __restrict__ Wi_o, const float* __restrict__ Wi_c,
              const float* __restrict__ Wh_f, const float* __restrict__ Wh_i,
              const float* __restrict__ Wh_o, const float* __restrict__ Wh_c,
              const float* __restrict__ Wi_g, const float* __restrict__ Wh_g,
              const float* __restrict__ W_last, const float* __restrict__ x,
              const float* __restrict__ hidden0, const float* __restrict__ current0,
              bf16* __restrict__ WiCatI, bf16* __restrict__ WhFIO,
              bf16* __restrict__ WhCb, bf16* __restrict__ Wgb,
              bf16* __restrict__ WgH, bf16* __restrict__ Wlb,
              bf16* __restrict__ xb, bf16* __restrict__ hcat, float* __restrict__ c0)
{
    int idx = blockIdx.x * 256 + threadIdx.x;
    if (idx < 786432) {                                   // WiCatI: n = 4j+gate
        int k = idx & 255, n = (idx >> 8) & 1023, l = idx >> 18;
        int j = n >> 2, g = n & 3;
        const float* src = (g == 0) ? Wi_f : (g == 1) ? Wi_i : (g == 2) ? Wi_o : Wi_c;
        WiCatI[idx] = __float2bfloat16(src[l * 65536 + j * 256 + k]);
        return;
    }
    idx -= 786432;
    if (idx < 589824) {                                   // WhFIO
        int k = idx & 255, n = (idx >> 8) % 768, l = idx / 196608;
        const float* src = (n < 256) ? Wh_f : (n < 512) ? Wh_i : Wh_o;
        WhFIO[idx] = __float2bfloat16(src[l * 65536 + (n & 255) * 256 + k]);
        return;
    }
    idx -= 589824;
    if (idx < 1769472) {                                  // WhCb convert
        WhCb[idx] = __float2bfloat16(Wh_c[idx]);
        return;
    }
    idx -= 1769472;
    if (idx < 12288) {                                    // Wgb [3][16][256]
        int k = idx & 255, r = (idx >> 8) & 15, l = idx >> 12;
        Wgb[idx] = (r < 3) ? __float2bfloat16(Wi_g[l * 768 + r * 256 + k])
                           : __float2bfloat16(0.f);
        return;
    }
    idx -= 12288;
    if (idx < 36864) {                                    // WgH [3][16][768]
        int k = idx % 768, r = (idx / 768) & 15, l = idx / (16 * 768);
        WgH[idx] = (r < 3) ? __float2bfloat16(Wh_g[(l * 3 + r) * 768 + k])
                           : __float2bfloat16(0.f);
        return;
    }
    idx -= 36864;
    if (idx < 294912) {                                   // Wlb [128][2304]
        int k = idx % 2304, n = idx / 2304;
        Wlb[idx] = (n < 44) ? __float2bfloat16(W_last[n * 2304 + k])
                            : __float2bfloat16(0.f);
        return;
    }
    idx -= 294912;
    if (idx < 1048576) {                                  // xb convert
        xb[idx] = __float2bfloat16(x[idx]);
        return;
    }
    idx -= 1048576;
    if (idx < 3145728) {                                  // state: hcat + c0
        int j = idx & 255, b = (idx >> 8) & 4095, l = idx >> 20;
        hcat[(size_t)b * 768 + l * 256 + j] = __float2bfloat16(hidden0[idx]);
        c0[idx] = current0[idx];
    }
}

extern "C" void kernel_launch(void* const* d_in, const int* in_sizes, int n_in,
                              void* d_out, int out_size, void* d_ws, size_t ws_size,
                              hipStream_t stream)
{
    (void)in_sizes; (void)n_in; (void)out_size; (void)ws_size;
    const float* x        = (const float*)d_in[0];
    const float* hidden0  = (const float*)d_in[1];
    const float* current0 = (const float*)d_in[2];
    const float* Wi_f = (const float*)d_in[3];  const float* bi_f = (const float*)d_in[4];
    const float* Wi_i = (const float*)d_in[5];  const float* bi_i = (const float*)d_in[6];
    const float* Wi_o = (const float*)d_in[7];  const float* bi_o = (const float*)d_in[8];
    const float* Wi_c = (const float*)d_in[9];  const float* bi_c = (const float*)d_in[10];
    const float* Wi_g = (const float*)d_in[11]; const float* bi_g = (const float*)d_in[12];
    const float* Wh_f = (const float*)d_in[13]; const float* bh_f = (const float*)d_in[14];
    const float* Wh_i = (const float*)d_in[15]; const float* bh_i = (const float*)d_in[16];
    const float* Wh_o = (const float*)d_in[17]; const float* bh_o = (const float*)d_in[18];
    const float* Wh_g = (const float*)d_in[19]; const float* bh_g = (const float*)d_in[20];
    const float* Wh_c = (const float*)d_in[21]; const float* bh_c = (const float*)d_in[22];
    const float* W_last = (const float*)d_in[23]; const float* b_last = (const float*)d_in[24];

    char* p = (char*)d_ws;
    bf16* WiCatI = (bf16*)p; p += (size_t)3 * 1024 * 256 * 2;
    bf16* WhFIO  = (bf16*)p; p += (size_t)3 * 768 * 256 * 2;
    bf16* WhCb   = (bf16*)p; p += (size_t)3 * 768 * 768 * 2;
    bf16* Wgb    = (bf16*)p; p += (size_t)3 * 16 * 256 * 2;
    bf16* WgH    = (bf16*)p; p += (size_t)3 * 16 * 768 * 2;
    bf16* Wlb    = (bf16*)p; p += (size_t)128 * 2304 * 2;
    bf16* xb     = (bf16*)p; p += (size_t)4096 * 256 * 2;
    bf16* ipre0i = (bf16*)p; p += (size_t)4096 * 1024 * 2;
    float* gin0  = (float*)p; p += (size_t)4096 * 3 * 4;
    bf16* hb0    = (bf16*)p; p += (size_t)4096 * 768 * 2;
    bf16* hb1    = (bf16*)p; p += (size_t)4096 * 768 * 2;
    float* cb0   = (float*)p; p += (size_t)3 * 4096 * 256 * 4;
    float* cb1   = (float*)p; p += (size_t)3 * 4096 * 256 * 4;
    bf16* hgb    = (bf16*)p; p += (size_t)3 * 4096 * 768 * 2;
    bf16* auxb   = (bf16*)p; p += (size_t)3 * 4096 * 768 * 2;
    float* gh    = (float*)p; p += (size_t)4096 * 9 * 4;
    bf16* feat   = (bf16*)p; p += (size_t)4096 * 2304 * 2;
    float* partf = (float*)p; p += (size_t)12 * 4096 * 64 * 4;

    // one merged prep launch: 7,684,096 elements
    prep_all<<<30017, 256, 0, stream>>>(
        Wi_f, Wi_i, Wi_o, Wi_c, Wh_f, Wh_i, Wh_o, Wh_c, Wi_g, Wh_g, W_last, x,
        hidden0, current0,
        WiCatI, WhFIO, WhCb, Wgb, WgH, Wlb, xb, hb0, cb0);

    // hoisted layer-0 input-side work (x constant across t)
    gemm_bt<<<dim3(8, 32, 1), 256, 0, stream>>>(xb, 256, 0, WiCatI, 256, 0,
                                                ipre0i, 1024, 0, 256, 1, nullptr, 0);
    gin0_kernel<<<256, 256, 0, stream>>>(xb, Wi_g, gin0);

    for (int t = 0; t < 10; ++t) {
        bf16* hprev = (t & 1) ? hb1 : hb0;
        bf16* hnew  = (t & 1) ? hb0 : hb1;
        float* cprev = (t & 1) ? cb1 : cb0;
        float* cnew  = (t & 1) ? cb0 : cb1;

        gemm_hidden<<<dim3(36, 32), 256, 0, stream>>>(
            hprev, WhFIO, WhCb, WgH, bi_g, bh_g, hgb, auxb, gh);

        gates_pre<<<1024, 256, 0, stream>>>(
            ipre0i, gin0, gh,
            hgb, auxb, cprev,
            bi_f, bh_f, bi_i, bh_i, bi_o, bh_o, bi_c, bh_c,
            hnew, cnew);

        for (int l = 1; l < 3; ++l) {
            gemm_gates<<<dim3(8, 64), 256, 0, stream>>>(
                (const bf16*)(hnew + (l - 1) * 256), 768,
                WiCatI + (size_t)l * 1024 * 256,
                Wgb + (size_t)l * 16 * 256,
                hgb + (size_t)l * 4096 * 768,
                auxb + (size_t)l * 4096 * 768,
                gh + l * 3,
                cprev + (size_t)l * 4096 * 256,
                bi_f + l * 256, bh_f + l * 256,
                bi_i + l * 256, bh_i + l * 256,
                bi_o + l * 256, bh_o + l * 256,
                bi_c + l * 256, bh_c + l * 768,
                hnew + l * 256,
                cnew + (size_t)l * 4096 * 256,
                (l == 2 && t < 9) ? (feat + (size_t)t * 256) : (bf16*)nullptr);
        }
    }

    // final: K-split feat[4096,2304] @ Wlb[128,2304]^T into 12 partials of K=192
    gemm_bt<<<dim3(1, 32, 12), 256, 0, stream>>>(
        feat, 2304, 192, Wlb, 2304, 192,
        partf, 64, (long long)4096 * 64, 192, 3, nullptr, 64);
    final_reduce<<<704, 256, 0, stream>>>(partf, b_last, (float*)d_out);
}

// Round 13
// 782.909 us; speedup vs baseline: 1.5182x; 1.0525x over previous
//
#include <hip/hip_runtime.h>
#include <hip/hip_bf16.h>

typedef __hip_bfloat16 bf16;
typedef __attribute__((ext_vector_type(8))) short frag8;   // 8 bf16 = 4 VGPRs
typedef __attribute__((ext_vector_type(4))) float f32x4;

#define BM 128
#define BN 128
#define BK 64
#define SK 72   // padded LDS stride for VGPR-staged kernels

__device__ __forceinline__ float sigm(float x) { return 1.f / (1.f + __expf(-x)); }

// async global->LDS, 16B/lane; lds base wave-uniform, lane scatters at +lane*16
__device__ __forceinline__ void lds_load16(const bf16* g, short* l) {
    __builtin_amdgcn_global_load_lds(
        (const __attribute__((address_space(1))) void*)g,
        (__attribute__((address_space(3))) void*)l, 16, 0, 0);
}

// C[m,n] = sum_k A[m,k] * W[n,k]; 128x128 tile, padded in-loop VGPR staging.
// outmode: 0 fp32, 1 bf16, 2 sigmoid(acc+bias[n]) fp32 n<nbound, 3 raw fp32 n<nbound.
// Optional g-side: if Wg != null, blockIdx.x==0 blocks also compute A @ Wg[0..15]^T
// (16-row zero-padded fragment) and write rows' first 3 cols to gout[row*3+s].
__global__ __launch_bounds__(256, 2)
void gemm_bt(const bf16* __restrict__ A, int lda, long long sAz,
             const bf16* __restrict__ W, int ldw, long long sWz,
             void* __restrict__ Cv, int ldc, long long sCz, int K,
             int outmode, const float* __restrict__ bias, int nbound,
             const bf16* __restrict__ Wg, float* __restrict__ gout)
{
    __shared__ short As[BM * SK];
    __shared__ short Bs[BN * SK];
    __shared__ short Bg[16 * SK];
    const int z = blockIdx.z;
    A += (size_t)z * sAz;
    W += (size_t)z * sWz;
    const int m0 = blockIdx.y * BM;
    const int n0 = blockIdx.x * BN;
    const int tid  = threadIdx.x;
    const int lane = tid & 63;
    const int wave = tid >> 6;
    const int wm = (wave >> 1) * 64;
    const int wn = (wave & 1) * 64;
    const int q   = lane >> 4;
    const int r16 = lane & 15;
    const bool do_g = (Wg != nullptr) && (blockIdx.x == 0);

    f32x4 acc[4][4] = {};
    f32x4 accg[4] = {};

    const int trow = tid >> 3;         // 0..31
    const int tcol = (tid & 7) * 8;    // 16B chunk (bf16 elems)

    for (int k0 = 0; k0 < K; k0 += BK) {
        __syncthreads();
        #pragma unroll
        for (int p = 0; p < 4; ++p) {
            int rr = p * 32 + trow;
            *(uint4*)&As[rr * SK + tcol] =
                *(const uint4*)(A + (size_t)(m0 + rr) * lda + k0 + tcol);
            *(uint4*)&Bs[rr * SK + tcol] =
                *(const uint4*)(W + (size_t)(n0 + rr) * ldw + k0 + tcol);
        }
        if (do_g && tid < 128)
            *(uint4*)&Bg[(tid >> 3) * SK + tcol] =
                *(const uint4*)(Wg + (size_t)(tid >> 3) * 256 + k0 + tcol);
        __syncthreads();
        #pragma unroll
        for (int kk = 0; kk < 2; ++kk) {
            const int ko = kk * 32 + q * 8;
            frag8 af[4], bfr[4];
            #pragma unroll
            for (int i = 0; i < 4; ++i)
                af[i] = *(const frag8*)&As[(wm + i * 16 + r16) * SK + ko];
            #pragma unroll
            for (int j = 0; j < 4; ++j)
                bfr[j] = *(const frag8*)&Bs[(wn + j * 16 + r16) * SK + ko];
            #pragma unroll
            for (int i = 0; i < 4; ++i)
                #pragma unroll
                for (int j = 0; j < 4; ++j)
                    acc[i][j] = __builtin_amdgcn_mfma_f32_16x16x32_bf16(
                        af[i], bfr[j], acc[i][j], 0, 0, 0);
            if (do_g) {
                frag8 bg = *(const frag8*)&Bg[r16 * SK + ko];
                #pragma unroll
                for (int i = 0; i < 4; ++i)
                    accg[i] = __builtin_amdgcn_mfma_f32_16x16x32_bf16(
                        af[i], bg, accg[i], 0, 0, 0);
            }
        }
    }

    if (outmode == 0) {
        float* C = (float*)Cv + (size_t)z * sCz;
        #pragma unroll
        for (int i = 0; i < 4; ++i)
            #pragma unroll
            for (int rr = 0; rr < 4; ++rr) {
                int row = m0 + wm + i * 16 + q * 4 + rr;
                float* crow = C + (size_t)row * ldc + n0 + wn + r16;
                #pragma unroll
                for (int j = 0; j < 4; ++j) crow[j * 16] = acc[i][j][rr];
            }
    } else if (outmode == 1) {
        bf16* C = (bf16*)Cv + (size_t)z * sCz;
        #pragma unroll
        for (int i = 0; i < 4; ++i)
            #pragma unroll
            for (int rr = 0; rr < 4; ++rr) {
                int row = m0 + wm + i * 16 + q * 4 + rr;
                bf16* crow = C + (size_t)row * ldc + n0 + wn + r16;
                #pragma unroll
                for (int j = 0; j < 4; ++j) crow[j * 16] = __float2bfloat16(acc[i][j][rr]);
            }
    } else if (outmode == 2) {
        float* C = (float*)Cv + (size_t)z * sCz;
        #pragma unroll
        for (int i = 0; i < 4; ++i)
            #pragma unroll
            for (int rr = 0; rr < 4; ++rr) {
                int row = m0 + wm + i * 16 + q * 4 + rr;
                #pragma unroll
                for (int j = 0; j < 4; ++j) {
                    int col = n0 + wn + j * 16 + r16;
                    if (col < nbound)
                        C[(size_t)row * ldc + col] = sigm(acc[i][j][rr] + bias[col]);
                }
            }
    } else {
        float* C = (float*)Cv + (size_t)z * sCz;
        #pragma unroll
        for (int i = 0; i < 4; ++i)
            #pragma unroll
            for (int rr = 0; rr < 4; ++rr) {
                int row = m0 + wm + i * 16 + q * 4 + rr;
                #pragma unroll
                for (int j = 0; j < 4; ++j) {
                    int col = n0 + wn + j * 16 + r16;
                    if (col < nbound)
                        C[(size_t)row * ldc + col] = acc[i][j][rr];
                }
            }
    }
    if (do_g && wn == 0 && r16 < 3) {
        #pragma unroll
        for (int i = 0; i < 4; ++i)
            #pragma unroll
            for (int rr = 0; rr < 4; ++rr) {
                int row = m0 + wm + i * 16 + q * 4 + rr;
                gout[(size_t)row * 3 + r16] = accg[i][rr];
            }
    }
}

// ---------------- merged hidden-side kernel (async staging + XOR-swizzled LDS) ----------------
// Grid (36, 32): zi = x%6, xt = x/6. XOR swizzle: 0 bank conflicts (verified r10/r11).
// launch_bounds(256,3): 76 VGPR + 80 AGPR = 156 <= 512/3 = 170 cap; no spill (r12 WRITE clean).
__global__ __launch_bounds__(256, 3)
void gemm_hidden(const bf16* __restrict__ hprev,
                 const bf16* __restrict__ WhFIO,  // [3][768][256]
                 const bf16* __restrict__ WhCb,   // [3][768][768]
                 const bf16* __restrict__ WgH,    // [3][16][768], rows 0..2 = Wh_g[l]
                 const float* __restrict__ big, const float* __restrict__ bhg,  // [9]
                 bf16* __restrict__ hgb,          // [3][4096][768]
                 bf16* __restrict__ auxb,         // [3][4096][768]
                 float* __restrict__ gh)          // [4096][9]
{
    __shared__ __align__(16) short As[BM * 64];
    __shared__ __align__(16) short Bs[BN * 64];
    __shared__ __align__(16) short Bg[16 * 64];

    const int zi = blockIdx.x % 6;
    const int xt = blockIdx.x / 6;
    const bool isaux = zi >= 3;
    const int l = isaux ? zi - 3 : zi;
    const bf16* A = hprev + (isaux ? 0 : l * 256);
    const int K = isaux ? 768 : 256;
    const bf16* W = isaux ? (WhCb + (size_t)l * 768 * 768) : (WhFIO + (size_t)l * 768 * 256);
    const int ldw = isaux ? 768 : 256;
    bf16* C = (isaux ? auxb : hgb) + (size_t)l * 4096 * 768;
    const bool do_g = isaux && (xt == 0);

    const int m0 = blockIdx.y * BM;
    const int n0 = xt * BN;
    const int tid  = threadIdx.x;
    const int lane = tid & 63;
    const int wave = tid >> 6;
    const int wm = (wave >> 1) * 64;
    const int wn = (wave & 1) * 64;
    const int q   = lane >> 4;
    const int r16 = lane & 15;

    f32x4 acc[4][4] = {};
    f32x4 accg[4] = {};

    const int srow = lane >> 3;                      // 0..7 row within 8-row chunk
    const int scolsw = ((lane & 7) ^ srow) * 8;      // XOR-swizzled source chunk
    const bf16* WgL = WgH + (size_t)l * 16 * 768;

    for (int k0 = 0; k0 < K; k0 += BK) {
        __syncthreads();
        #pragma unroll
        for (int p = 0; p < 4; ++p) {
            int rbase = (wave * 4 + p) * 8;
            lds_load16(A + (size_t)(m0 + rbase + srow) * 768 + k0 + scolsw, &As[rbase * 64]);
            lds_load16(W + (size_t)(n0 + rbase + srow) * ldw + k0 + scolsw, &Bs[rbase * 64]);
        }
        if (do_g && wave < 2)
            lds_load16(WgL + (size_t)(wave * 8 + srow) * 768 + k0 + scolsw, &Bg[wave * 8 * 64]);
        __syncthreads();
        #pragma unroll
        for (int kk = 0; kk < 2; ++kk) {
            const int c = kk * 4 + q;   // k-chunk index 0..7
            frag8 af[4], bfr[4];
            #pragma unroll
            for (int i = 0; i < 4; ++i) {
                int R = wm + i * 16 + r16;
                af[i] = *(const frag8*)&As[R * 64 + ((c ^ (R & 7)) << 3)];
            }
            #pragma unroll
            for (int j = 0; j < 4; ++j) {
                int R = wn + j * 16 + r16;
                bfr[j] = *(const frag8*)&Bs[R * 64 + ((c ^ (R & 7)) << 3)];
            }
            #pragma unroll
            for (int i = 0; i < 4; ++i)
                #pragma unroll
                for (int j = 0; j < 4; ++j)
                    acc[i][j] = __builtin_amdgcn_mfma_f32_16x16x32_bf16(
                        af[i], bfr[j], acc[i][j], 0, 0, 0);
            if (do_g) {
                frag8 bg = *(const frag8*)&Bg[r16 * 64 + ((c ^ (r16 & 7)) << 3)];
                #pragma unroll
                for (int i = 0; i < 4; ++i)
                    accg[i] = __builtin_amdgcn_mfma_f32_16x16x32_bf16(
                        af[i], bg, accg[i], 0, 0, 0);
            }
        }
    }

    #pragma unroll
    for (int i = 0; i < 4; ++i)
        #pragma unroll
        for (int rr = 0; rr < 4; ++rr) {
            int row = m0 + wm + i * 16 + q * 4 + rr;
            bf16* crow = C + (size_t)row * 768 + n0 + wn + r16;
            #pragma unroll
            for (int j = 0; j < 4; ++j) crow[j * 16] = __float2bfloat16(acc[i][j][rr]);
        }
    if (do_g && wn == 0 && r16 < 3) {
        float bsum = big[l * 3 + r16] + bhg[l * 3 + r16];
        #pragma unroll
        for (int i = 0; i < 4; ++i)
            #pragma unroll
            for (int rr = 0; rr < 4; ++rr) {
                int row = m0 + wm + i * 16 + q * 4 + rr;
                gh[(size_t)row * 9 + l * 3 + r16] = accg[i][rr] + bsum;
            }
    }
}

// ---------------- fused input-GEMM + gates (layers 1,2) ----------------
// 32m x 128n tile, grid (8, 128) = 1024 blocks ~ 4/CU natural occupancy (small-K GEMM is
// latency-bound; more resident blocks hide the barrier drain). Async staging + XOR swizzle.
#define GM 32
struct Stage { short As[GM * 64]; short Bs[BN * 64]; short Bg[16 * 64]; };
union SMemU { Stage s; float ct[GM * 128]; };

__global__ __launch_bounds__(256, 2)
void gemm_gates(const bf16* __restrict__ A, int lda,
                const bf16* __restrict__ Wi, const bf16* __restrict__ Wg,
                const bf16* __restrict__ hg_l,   // [4096][768] bf16
                const bf16* __restrict__ aux_l,  // [4096][768] bf16
                const float* __restrict__ ghc_l, // gh + l*3, stride 9, biases folded
                const float* __restrict__ cprev,
                const float* __restrict__ bif, const float* __restrict__ bhf,
                const float* __restrict__ bii, const float* __restrict__ bhi,
                const float* __restrict__ bio, const float* __restrict__ bho,
                const float* __restrict__ bic, const float* __restrict__ bhc, // [768]
                bf16*  __restrict__ hnew,   // col-slice base, row stride 768
                float* __restrict__ cnew,
                bf16*  __restrict__ featc)  // nullable, row stride 2304
{
    __shared__ __align__(16) SMemU sm;
    __shared__ float gsh[GM * 3];

    const int m0 = blockIdx.y * GM;
    const int n0 = blockIdx.x * BN;
    const int jbase = n0 >> 2;
    const int tid  = threadIdx.x;
    const int lane = tid & 63;
    const int wave = tid >> 6;
    const int wm = (wave >> 1) * 16;   // 2x2 waves, each 16m x 64n
    const int wn = (wave & 1) * 64;
    const int q   = lane >> 4;
    const int r16 = lane & 15;

    f32x4 acc[4] = {};
    f32x4 accg = {};

    const int srow = lane >> 3;
    const int scolsw = ((lane & 7) ^ srow) * 8;

    for (int k0 = 0; k0 < 256; k0 += BK) {
        __syncthreads();
        // A: 32 rows = 4 chunks, one per wave
        lds_load16(A + (size_t)(m0 + wave * 8 + srow) * lda + k0 + scolsw,
                   &sm.s.As[wave * 8 * 64]);
        #pragma unroll
        for (int p = 0; p < 4; ++p) {
            int rbase = (wave * 4 + p) * 8;   // B: 128 rows = 16 chunks
            lds_load16(Wi + (size_t)(n0 + rbase + srow) * 256 + k0 + scolsw, &sm.s.Bs[rbase * 64]);
        }
        if (wave < 2)
            lds_load16(Wg + (size_t)(wave * 8 + srow) * 256 + k0 + scolsw, &sm.s.Bg[wave * 8 * 64]);
        __syncthreads();
        #pragma unroll
        for (int kk = 0; kk < 2; ++kk) {
            const int c = kk * 4 + q;
            frag8 af, bfr[4], bg;
            bg = *(const frag8*)&sm.s.Bg[r16 * 64 + ((c ^ (r16 & 7)) << 3)];
            {
                int R = wm + r16;
                af = *(const frag8*)&sm.s.As[R * 64 + ((c ^ (R & 7)) << 3)];
            }
            #pragma unroll
            for (int j = 0; j < 4; ++j) {
                int R = wn + j * 16 + r16;
                bfr[j] = *(const frag8*)&sm.s.Bs[R * 64 + ((c ^ (R & 7)) << 3)];
            }
            #pragma unroll
            for (int j = 0; j < 4; ++j)
                acc[j] = __builtin_amdgcn_mfma_f32_16x16x32_bf16(af, bfr[j], acc[j], 0, 0, 0);
            accg = __builtin_amdgcn_mfma_f32_16x16x32_bf16(af, bg, accg, 0, 0, 0);
        }
    }

    __syncthreads();   // staging reads done; sm union becomes ct
    // g values: waves with wn==0 (0 and 2) cover rows 0..31
    if (wn == 0 && r16 < 3) {
        #pragma unroll
        for (int rr = 0; rr < 4; ++rr) {
            int row = wm + q * 4 + rr;
            gsh[row * 3 + r16] = sigm(accg[rr] + ghc_l[(size_t)(m0 + row) * 9 + r16]);
        }
    }
    // dump C tile (rotate-swizzled float4 groups)
    #pragma unroll
    for (int rr = 0; rr < 4; ++rr) {
        int rowl = wm + q * 4 + rr;
        #pragma unroll
        for (int jr = 0; jr < 4; ++jr) {
            int col = wn + jr * 16 + r16;
            sm.ct[rowl * 128 + ((col + 4 * rowl) & 127)] = acc[jr][rr];
        }
    }
    __syncthreads();

    const int jj = tid & 31;
    const int r0 = (tid >> 5) * 4;
    const int j  = jbase + jj;
    const float vbif = bif[j], vbhf = bhf[j];
    const float vbii = bii[j], vbhi = bhi[j];
    const float vbio = bio[j], vbho = bho[j];
    const float vbic = bic[j];
    const float vbc0 = bhc[j], vbc1 = bhc[256 + j], vbc2 = bhc[512 + j];

    #pragma unroll
    for (int ri = 0; ri < 4; ++ri) {
        int rowl = r0 + ri;
        size_t b = m0 + rowl;
        float4 pre = *(float4*)&sm.ct[rowl * 128 + ((4 * jj + 4 * rowl) & 127)];
        float g0 = gsh[rowl * 3 + 0];
        float g1 = gsh[rowl * 3 + 1];
        float g2 = gsh[rowl * 3 + 2];
        float hgf = __bfloat162float(hg_l[b * 768 + j]);
        float hgi = __bfloat162float(hg_l[b * 768 + 256 + j]);
        float hgo = __bfloat162float(hg_l[b * 768 + 512 + j]);
        float ax0 = __bfloat162float(aux_l[b * 768 + j]);
        float ax1 = __bfloat162float(aux_l[b * 768 + 256 + j]);
        float ax2 = __bfloat162float(aux_l[b * 768 + 512 + j]);
        float f  = sigm(pre.x + vbif + hgf + vbhf);
        float ii = sigm(pre.y + vbii + hgi + vbhi);
        float o  = sigm(pre.z + vbio + hgo + vbho);
        float av = g0 * (ax0 + vbc0) + g1 * (ax1 + vbc1) + g2 * (ax2 + vbc2);
        float ct = tanhf(pre.w + vbic + av);
        float c  = f * cprev[b * 256 + j] + ii * ct;
        float h  = o * c;
        cnew[b * 256 + j] = c;
        hnew[b * 768 + j] = __float2bfloat16(h);
        if (featc) featc[b * 2304 + j] = __float2bfloat16(h);
    }
}

// ---------------- layer-0 gates from precomputed pre-acts ----------------
// 1024 blocks x 4 rows
__global__ __launch_bounds__(256)
void gates_pre(const bf16* __restrict__ ipre0i, const float* __restrict__ gin0,
               const float* __restrict__ ghc,
               const bf16* __restrict__ hg_l, const bf16* __restrict__ aux_l,
               const float* __restrict__ cprev,
               const float* __restrict__ bif, const float* __restrict__ bhf,
               const float* __restrict__ bii, const float* __restrict__ bhi,
               const float* __restrict__ bio, const float* __restrict__ bho,
               const float* __restrict__ bic, const float* __restrict__ bhc,
               bf16* __restrict__ hnew, float* __restrict__ cnew)
{
    const int j = threadIdx.x;
    const int b0 = blockIdx.x * 4;
    const float vbif = bif[j], vbhf = bhf[j];
    const float vbii = bii[j], vbhi = bhi[j];
    const float vbio = bio[j], vbho = bho[j];
    const float vbic = bic[j];
    const float vbc0 = bhc[j], vbc1 = bhc[256 + j], vbc2 = bhc[512 + j];

    #pragma unroll
    for (int r = 0; r < 4; ++r) {
        const size_t b = b0 + r;
        const bf16* ip4 = ipre0i + b * 1024 + 4 * j;
        float pf = __bfloat162float(ip4[0]);
        float pi = __bfloat162float(ip4[1]);
        float po = __bfloat162float(ip4[2]);
        float pc = __bfloat162float(ip4[3]);
        float g0 = sigm(gin0[b * 3 + 0] + ghc[b * 9 + 0]);
        float g1 = sigm(gin0[b * 3 + 1] + ghc[b * 9 + 1]);
        float g2 = sigm(gin0[b * 3 + 2] + ghc[b * 9 + 2]);
        float hgf = __bfloat162float(hg_l[b * 768 + j]);
        float hgi = __bfloat162float(hg_l[b * 768 + 256 + j]);
        float hgo = __bfloat162float(hg_l[b * 768 + 512 + j]);
        float ax0 = __bfloat162float(aux_l[b * 768 + j]);
        float ax1 = __bfloat162float(aux_l[b * 768 + 256 + j]);
        float ax2 = __bfloat162float(aux_l[b * 768 + 512 + j]);
        float f  = sigm(pf + vbif + hgf + vbhf);
        float ii = sigm(pi + vbii + hgi + vbhi);
        float o  = sigm(po + vbio + hgo + vbho);
        float av = g0 * (ax0 + vbc0) + g1 * (ax1 + vbc1) + g2 * (ax2 + vbc2);
        float ct = tanhf(pc + vbic + av);
        float c  = f * cprev[b * 256 + j] + ii * ct;
        float h  = o * c;
        cnew[b * 256 + j] = c;
        hnew[b * 768 + j] = __float2bfloat16(h);
    }
}

// out[b][n] = sigm(bias[n] + sum_z part[z][b][n]), n<44
__global__ __launch_bounds__(256)
void final_reduce(const float* __restrict__ part, const float* __restrict__ bl,
                  float* __restrict__ out)
{
    int idx = blockIdx.x * 256 + threadIdx.x;
    if (idx >= 4096 * 44) return;
    int b = idx / 44, n = idx - b * 44;
    float s = bl[n];
    #pragma unroll
    for (int z = 0; z < 12; ++z) s += part[(size_t)z * 4096 * 64 + (size_t)b * 64 + n];
    out[idx] = sigm(s);
}

// ---------------- single merged prep kernel ----------------
__global__ __launch_bounds__(256)
void prep_all(const float* __restrict__ Wi_f, const float* __restrict__ Wi_i,
              const float* __restrict__ Wi_o, const float* __restrict__ Wi_c,
              const float* __restrict__ Wh_f, const float* __restrict__ Wh_i,
              const float* __restrict__ Wh_o, const float* __restrict__ Wh_c,
              const float* __restrict__ Wi_g, const float* __restrict__ Wh_g,
              const float* __restrict__ W_last, const float* __restrict__ x,
              const float* __restrict__ hidden0, const float* __restrict__ current0,
              bf16* __restrict__ WiCatI, bf16* __restrict__ WhFIO,
              bf16* __restrict__ WhCb, bf16* __restrict__ Wgb,
              bf16* __restrict__ WgH, bf16* __restrict__ Wlb,
              bf16* __restrict__ xb, bf16* __restrict__ hcat, float* __restrict__ c0)
{
    int idx = blockIdx.x * 256 + threadIdx.x;
    if (idx < 786432) {                                   // WiCatI: n = 4j+gate
        int k = idx & 255, n = (idx >> 8) & 1023, l = idx >> 18;
        int j = n >> 2, g = n & 3;
        const float* src = (g == 0) ? Wi_f : (g == 1) ? Wi_i : (g == 2) ? Wi_o : Wi_c;
        WiCatI[idx] = __float2bfloat16(src[l * 65536 + j * 256 + k]);
        return;
    }
    idx -= 786432;
    if (idx < 589824) {                                   // WhFIO
        int k = idx & 255, n = (idx >> 8) % 768, l = idx / 196608;
        const float* src = (n < 256) ? Wh_f : (n < 512) ? Wh_i : Wh_o;
        WhFIO[idx] = __float2bfloat16(src[l * 65536 + (n & 255) * 256 + k]);
        return;
    }
    idx -= 589824;
    if (idx < 1769472) {                                  // WhCb convert
        WhCb[idx] = __float2bfloat16(Wh_c[idx]);
        return;
    }
    idx -= 1769472;
    if (idx < 12288) {                                    // Wgb [3][16][256]
        int k = idx & 255, r = (idx >> 8) & 15, l = idx >> 12;
        Wgb[idx] = (r < 3) ? __float2bfloat16(Wi_g[l * 768 + r * 256 + k])
                           : __float2bfloat16(0.f);
        return;
    }
    idx -= 12288;
    if (idx < 36864) {                                    // WgH [3][16][768]
        int k = idx % 768, r = (idx / 768) & 15, l = idx / (16 * 768);
        WgH[idx] = (r < 3) ? __float2bfloat16(Wh_g[(l * 3 + r) * 768 + k])
                           : __float2bfloat16(0.f);
        return;
    }
    idx -= 36864;
    if (idx < 294912) {                                   // Wlb [128][2304]
        int k = idx % 2304, n = idx / 2304;
        Wlb[idx] = (n < 44) ? __float2bfloat16(W_last[n * 2304 + k])
                            : __float2bfloat16(0.f);
        return;
    }
    idx -= 294912;
    if (idx < 1048576) {                                  // xb convert
        xb[idx] = __float2bfloat16(x[idx]);
        return;
    }
    idx -= 1048576;
    if (idx < 3145728) {                                  // state: hcat + c0
        int j = idx & 255, b = (idx >> 8) & 4095, l = idx >> 20;
        hcat[(size_t)b * 768 + l * 256 + j] = __float2bfloat16(hidden0[idx]);
        c0[idx] = current0[idx];
    }
}

extern "C" void kernel_launch(void* const* d_in, const int* in_sizes, int n_in,
                              void* d_out, int out_size, void* d_ws, size_t ws_size,
                              hipStream_t stream)
{
    (void)in_sizes; (void)n_in; (void)out_size; (void)ws_size;
    const float* x        = (const float*)d_in[0];
    const float* hidden0  = (const float*)d_in[1];
    const float* current0 = (const float*)d_in[2];
    const float* Wi_f = (const float*)d_in[3];  const float* bi_f = (const float*)d_in[4];
    const float* Wi_i = (const float*)d_in[5];  const float* bi_i = (const float*)d_in[6];
    const float* Wi_o = (const float*)d_in[7];  const float* bi_o = (const float*)d_in[8];
    const float* Wi_c = (const float*)d_in[9];  const float* bi_c = (const float*)d_in[10];
    const float* Wi_g = (const float*)d_in[11]; const float* bi_g = (const float*)d_in[12];
    const float* Wh_f = (const float*)d_in[13]; const float* bh_f = (const float*)d_in[14];
    const float* Wh_i = (const float*)d_in[15]; const float* bh_i = (const float*)d_in[16];
    const float* Wh_o = (const float*)d_in[17]; const float* bh_o = (const float*)d_in[18];
    const float* Wh_g = (const float*)d_in[19]; const float* bh_g = (const float*)d_in[20];
    const float* Wh_c = (const float*)d_in[21]; const float* bh_c = (const float*)d_in[22];
    const float* W_last = (const float*)d_in[23]; const float* b_last = (const float*)d_in[24];

    char* p = (char*)d_ws;
    bf16* WiCatI = (bf16*)p; p += (size_t)3 * 1024 * 256 * 2;
    bf16* WhFIO  = (bf16*)p; p += (size_t)3 * 768 * 256 * 2;
    bf16* WhCb   = (bf16*)p; p += (size_t)3 * 768 * 768 * 2;
    bf16* Wgb    = (bf16*)p; p += (size_t)3 * 16 * 256 * 2;
    bf16* WgH    = (bf16*)p; p += (size_t)3 * 16 * 768 * 2;
    bf16* Wlb    = (bf16*)p; p += (size_t)128 * 2304 * 2;
    bf16* xb     = (bf16*)p; p += (size_t)4096 * 256 * 2;
    bf16* ipre0i = (bf16*)p; p += (size_t)4096 * 1024 * 2;
    float* gin0  = (float*)p; p += (size_t)4096 * 3 * 4;
    bf16* hb0    = (bf16*)p; p += (size_t)4096 * 768 * 2;
    bf16* hb1    = (bf16*)p; p += (size_t)4096 * 768 * 2;
    float* cb0   = (float*)p; p += (size_t)3 * 4096 * 256 * 4;
    float* cb1   = (float*)p; p += (size_t)3 * 4096 * 256 * 4;
    bf16* hgb    = (bf16*)p; p += (size_t)3 * 4096 * 768 * 2;
    bf16* auxb   = (bf16*)p; p += (size_t)3 * 4096 * 768 * 2;
    float* gh    = (float*)p; p += (size_t)4096 * 9 * 4;
    bf16* feat   = (bf16*)p; p += (size_t)4096 * 2304 * 2;
    float* partf = (float*)p; p += (size_t)12 * 4096 * 64 * 4;

    // one merged prep launch: 7,684,096 elements
    prep_all<<<30017, 256, 0, stream>>>(
        Wi_f, Wi_i, Wi_o, Wi_c, Wh_f, Wh_i, Wh_o, Wh_c, Wi_g, Wh_g, W_last, x,
        hidden0, current0,
        WiCatI, WhFIO, WhCb, Wgb, WgH, Wlb, xb, hb0, cb0);

    // hoisted layer-0 input-side work (x constant across t); gin0 rides as Bg fragment
    gemm_bt<<<dim3(8, 32, 1), 256, 0, stream>>>(xb, 256, 0, WiCatI, 256, 0,
                                                ipre0i, 1024, 0, 256, 1, nullptr, 0,
                                                Wgb, gin0);

    for (int t = 0; t < 10; ++t) {
        bf16* hprev = (t & 1) ? hb1 : hb0;
        bf16* hnew  = (t & 1) ? hb0 : hb1;
        float* cprev = (t & 1) ? cb1 : cb0;
        float* cnew  = (t & 1) ? cb0 : cb1;

        gemm_hidden<<<dim3(36, 32), 256, 0, stream>>>(
            hprev, WhFIO, WhCb, WgH, bi_g, bh_g, hgb, auxb, gh);

        gates_pre<<<1024, 256, 0, stream>>>(
            ipre0i, gin0, gh,
            hgb, auxb, cprev,
            bi_f, bh_f, bi_i, bh_i, bi_o, bh_o, bi_c, bh_c,
            hnew, cnew);

        for (int l = 1; l < 3; ++l) {
            gemm_gates<<<dim3(8, 128), 256, 0, stream>>>(
                (const bf16*)(hnew + (l - 1) * 256), 768,
                WiCatI + (size_t)l * 1024 * 256,
                Wgb + (size_t)l * 16 * 256,
                hgb + (size_t)l * 4096 * 768,
                auxb + (size_t)l * 4096 * 768,
                gh + l * 3,
                cprev + (size_t)l * 4096 * 256,
                bi_f + l * 256, bh_f + l * 256,
                bi_i + l * 256, bh_i + l * 256,
                bi_o + l * 256, bh_o + l * 256,
                bi_c + l * 256, bh_c + l * 768,
                hnew + l * 256,
                cnew + (size_t)l * 4096 * 256,
                (l == 2 && t < 9) ? (feat + (size_t)t * 256) : (bf16*)nullptr);
        }
    }

    // final: K-split feat[4096,2304] @ Wlb[128,2304]^T into 12 partials of K=192
    gemm_bt<<<dim3(1, 32, 12), 256, 0, stream>>>(
        feat, 2304, 192, Wlb, 2304, 192,
        partf, 64, (long long)4096 * 64, 192, 3, nullptr, 64,
        nullptr, nullptr);
    final_reduce<<<704, 256, 0, stream>>>(partf, b_last, (float*)d_out);
}

// Round 14
// 778.598 us; speedup vs baseline: 1.5266x; 1.0055x over previous
//
#include <hip/hip_runtime.h>
#include <hip/hip_bf16.h>

typedef __hip_bfloat16 bf16;
typedef __attribute__((ext_vector_type(8))) short frag8;   // 8 bf16 = 4 VGPRs
typedef __attribute__((ext_vector_type(4))) float f32x4;

#define BM 128
#define BN 128
#define BK 64

__device__ __forceinline__ float sigm(float x) { return 1.f / (1.f + __expf(-x)); }

// async global->LDS, 16B/lane; lds base wave-uniform, lane scatters at +lane*16
__device__ __forceinline__ void lds_load16(const bf16* g, short* l) {
    __builtin_amdgcn_global_load_lds(
        (const __attribute__((address_space(1))) void*)g,
        (__attribute__((address_space(3))) void*)l, 16, 0, 0);
}

// ---------------- 64x128 GEMM (async staging + XOR swizzle) ----------------
// C[m,n] = sum_k A[m,k]*W[n,k]. outmode: 1 = bf16 store, else raw fp32 for n<nbound.
// Optional g-side (Wg != null, blockIdx.x==0): A @ Wg[16 rows]^T, first 3 cols -> gout.
__global__ __launch_bounds__(256, 2)
void gemm_bt64(const bf16* __restrict__ A, int lda, long long sAz,
               const bf16* __restrict__ W, int ldw, long long sWz,
               void* __restrict__ Cv, int ldc, long long sCz, int K,
               int outmode, int nbound,
               const bf16* __restrict__ Wg, float* __restrict__ gout)
{
    __shared__ __align__(16) short As[64 * 64];
    __shared__ __align__(16) short Bs[BN * 64];
    __shared__ __align__(16) short Bg[16 * 64];
    const int z = blockIdx.z;
    A += (size_t)z * sAz;
    W += (size_t)z * sWz;
    const int m0 = blockIdx.y * 64;
    const int n0 = blockIdx.x * BN;
    const int tid  = threadIdx.x;
    const int lane = tid & 63;
    const int wave = tid >> 6;
    const int wm = (wave >> 1) * 32;   // 2x2 waves, each 32m x 64n
    const int wn = (wave & 1) * 64;
    const int q   = lane >> 4;
    const int r16 = lane & 15;
    const bool do_g = (Wg != nullptr) && (blockIdx.x == 0);

    f32x4 acc[2][4] = {};
    f32x4 accg[2] = {};

    const int srow = lane >> 3;
    const int scolsw = ((lane & 7) ^ srow) * 8;

    for (int k0 = 0; k0 < K; k0 += BK) {
        __syncthreads();
        #pragma unroll
        for (int p = 0; p < 2; ++p) {
            int rbase = (wave * 2 + p) * 8;   // A: 64 rows = 8 chunks
            lds_load16(A + (size_t)(m0 + rbase + srow) * lda + k0 + scolsw, &As[rbase * 64]);
        }
        #pragma unroll
        for (int p = 0; p < 4; ++p) {
            int rbase = (wave * 4 + p) * 8;   // B: 128 rows = 16 chunks
            lds_load16(W + (size_t)(n0 + rbase + srow) * ldw + k0 + scolsw, &Bs[rbase * 64]);
        }
        if (do_g && wave < 2)
            lds_load16(Wg + (size_t)(wave * 8 + srow) * lda + k0 + scolsw, &Bg[wave * 8 * 64]);
        __syncthreads();
        #pragma unroll
        for (int kk = 0; kk < 2; ++kk) {
            const int c = kk * 4 + q;
            frag8 af[2], bfr[4];
            #pragma unroll
            for (int i = 0; i < 2; ++i) {
                int R = wm + i * 16 + r16;
                af[i] = *(const frag8*)&As[R * 64 + ((c ^ (R & 7)) << 3)];
            }
            #pragma unroll
            for (int j = 0; j < 4; ++j) {
                int R = wn + j * 16 + r16;
                bfr[j] = *(const frag8*)&Bs[R * 64 + ((c ^ (R & 7)) << 3)];
            }
            #pragma unroll
            for (int i = 0; i < 2; ++i)
                #pragma unroll
                for (int j = 0; j < 4; ++j)
                    acc[i][j] = __builtin_amdgcn_mfma_f32_16x16x32_bf16(
                        af[i], bfr[j], acc[i][j], 0, 0, 0);
            if (do_g) {
                frag8 bg = *(const frag8*)&Bg[r16 * 64 + ((c ^ (r16 & 7)) << 3)];
                #pragma unroll
                for (int i = 0; i < 2; ++i)
                    accg[i] = __builtin_amdgcn_mfma_f32_16x16x32_bf16(
                        af[i], bg, accg[i], 0, 0, 0);
            }
        }
    }

    if (outmode == 1) {
        bf16* C = (bf16*)Cv + (size_t)z * sCz;
        #pragma unroll
        for (int i = 0; i < 2; ++i)
            #pragma unroll
            for (int rr = 0; rr < 4; ++rr) {
                int row = m0 + wm + i * 16 + q * 4 + rr;
                bf16* crow = C + (size_t)row * ldc + n0 + wn + r16;
                #pragma unroll
                for (int j = 0; j < 4; ++j) crow[j * 16] = __float2bfloat16(acc[i][j][rr]);
            }
    } else {
        float* C = (float*)Cv + (size_t)z * sCz;
        #pragma unroll
        for (int i = 0; i < 2; ++i)
            #pragma unroll
            for (int rr = 0; rr < 4; ++rr) {
                int row = m0 + wm + i * 16 + q * 4 + rr;
                #pragma unroll
                for (int j = 0; j < 4; ++j) {
                    int col = n0 + wn + j * 16 + r16;
                    if (col < nbound)
                        C[(size_t)row * ldc + col] = acc[i][j][rr];
                }
            }
    }
    if (do_g && wn == 0 && r16 < 3) {
        #pragma unroll
        for (int i = 0; i < 2; ++i)
            #pragma unroll
            for (int rr = 0; rr < 4; ++rr) {
                int row = m0 + wm + i * 16 + q * 4 + rr;
                gout[(size_t)row * 3 + r16] = accg[i][rr];
            }
    }
}

// ---------------- merged hidden-side kernel (async staging + XOR-swizzled LDS) ----------------
// Grid (36, 32): zi = x%6, xt = x/6. XOR swizzle: 0 bank conflicts (verified r10/r11).
// launch_bounds(256,3): 76 VGPR + 80 AGPR = 156 <= 512/3 = 170 cap; no spill (r12 WRITE clean).
__global__ __launch_bounds__(256, 3)
void gemm_hidden(const bf16* __restrict__ hprev,
                 const bf16* __restrict__ WhFIO,  // [3][768][256]
                 const bf16* __restrict__ WhCb,   // [3][768][768]
                 const bf16* __restrict__ WgH,    // [3][16][768], rows 0..2 = Wh_g[l]
                 const float* __restrict__ big, const float* __restrict__ bhg,  // [9]
                 bf16* __restrict__ hgb,          // [3][4096][768]
                 bf16* __restrict__ auxb,         // [3][4096][768]
                 float* __restrict__ gh)          // [4096][9]
{
    __shared__ __align__(16) short As[BM * 64];
    __shared__ __align__(16) short Bs[BN * 64];
    __shared__ __align__(16) short Bg[16 * 64];

    const int zi = blockIdx.x % 6;
    const int xt = blockIdx.x / 6;
    const bool isaux = zi >= 3;
    const int l = isaux ? zi - 3 : zi;
    const bf16* A = hprev + (isaux ? 0 : l * 256);
    const int K = isaux ? 768 : 256;
    const bf16* W = isaux ? (WhCb + (size_t)l * 768 * 768) : (WhFIO + (size_t)l * 768 * 256);
    const int ldw = isaux ? 768 : 256;
    bf16* C = (isaux ? auxb : hgb) + (size_t)l * 4096 * 768;
    const bool do_g = isaux && (xt == 0);

    const int m0 = blockIdx.y * BM;
    const int n0 = xt * BN;
    const int tid  = threadIdx.x;
    const int lane = tid & 63;
    const int wave = tid >> 6;
    const int wm = (wave >> 1) * 64;
    const int wn = (wave & 1) * 64;
    const int q   = lane >> 4;
    const int r16 = lane & 15;

    f32x4 acc[4][4] = {};
    f32x4 accg[4] = {};

    const int srow = lane >> 3;                      // 0..7 row within 8-row chunk
    const int scolsw = ((lane & 7) ^ srow) * 8;      // XOR-swizzled source chunk
    const bf16* WgL = WgH + (size_t)l * 16 * 768;

    for (int k0 = 0; k0 < K; k0 += BK) {
        __syncthreads();
        #pragma unroll
        for (int p = 0; p < 4; ++p) {
            int rbase = (wave * 4 + p) * 8;
            lds_load16(A + (size_t)(m0 + rbase + srow) * 768 + k0 + scolsw, &As[rbase * 64]);
            lds_load16(W + (size_t)(n0 + rbase + srow) * ldw + k0 + scolsw, &Bs[rbase * 64]);
        }
        if (do_g && wave < 2)
            lds_load16(WgL + (size_t)(wave * 8 + srow) * 768 + k0 + scolsw, &Bg[wave * 8 * 64]);
        __syncthreads();
        #pragma unroll
        for (int kk = 0; kk < 2; ++kk) {
            const int c = kk * 4 + q;   // k-chunk index 0..7
            frag8 af[4], bfr[4];
            #pragma unroll
            for (int i = 0; i < 4; ++i) {
                int R = wm + i * 16 + r16;
                af[i] = *(const frag8*)&As[R * 64 + ((c ^ (R & 7)) << 3)];
            }
            #pragma unroll
            for (int j = 0; j < 4; ++j) {
                int R = wn + j * 16 + r16;
                bfr[j] = *(const frag8*)&Bs[R * 64 + ((c ^ (R & 7)) << 3)];
            }
            #pragma unroll
            for (int i = 0; i < 4; ++i)
                #pragma unroll
                for (int j = 0; j < 4; ++j)
                    acc[i][j] = __builtin_amdgcn_mfma_f32_16x16x32_bf16(
                        af[i], bfr[j], acc[i][j], 0, 0, 0);
            if (do_g) {
                frag8 bg = *(const frag8*)&Bg[r16 * 64 + ((c ^ (r16 & 7)) << 3)];
                #pragma unroll
                for (int i = 0; i < 4; ++i)
                    accg[i] = __builtin_amdgcn_mfma_f32_16x16x32_bf16(
                        af[i], bg, accg[i], 0, 0, 0);
            }
        }
    }

    #pragma unroll
    for (int i = 0; i < 4; ++i)
        #pragma unroll
        for (int rr = 0; rr < 4; ++rr) {
            int row = m0 + wm + i * 16 + q * 4 + rr;
            bf16* crow = C + (size_t)row * 768 + n0 + wn + r16;
            #pragma unroll
            for (int j = 0; j < 4; ++j) crow[j * 16] = __float2bfloat16(acc[i][j][rr]);
        }
    if (do_g && wn == 0 && r16 < 3) {
        float bsum = big[l * 3 + r16] + bhg[l * 3 + r16];
        #pragma unroll
        for (int i = 0; i < 4; ++i)
            #pragma unroll
            for (int rr = 0; rr < 4; ++rr) {
                int row = m0 + wm + i * 16 + q * 4 + rr;
                gh[(size_t)row * 9 + l * 3 + r16] = accg[i][rr] + bsum;
            }
    }
}

// ---------------- fused input-GEMM + gates (layers 1,2) ----------------
// 32m x 128n tile, grid (8, 128) = 1024 blocks ~ 4/CU. Async staging + XOR swizzle.
#define GM 32
struct Stage { short As[GM * 64]; short Bs[BN * 64]; short Bg[16 * 64]; };
union SMemU { Stage s; float ct[GM * 128]; };

__global__ __launch_bounds__(256, 2)
void gemm_gates(const bf16* __restrict__ A, int lda,
                const bf16* __restrict__ Wi, const bf16* __restrict__ Wg,
                const bf16* __restrict__ hg_l,   // [4096][768] bf16
                const bf16* __restrict__ aux_l,  // [4096][768] bf16
                const float* __restrict__ ghc_l, // gh + l*3, stride 9, biases folded
                const float* __restrict__ cprev,
                const float* __restrict__ bif, const float* __restrict__ bhf,
                const float* __restrict__ bii, const float* __restrict__ bhi,
                const float* __restrict__ bio, const float* __restrict__ bho,
                const float* __restrict__ bic, const float* __restrict__ bhc, // [768]
                bf16*  __restrict__ hnew,   // col-slice base, row stride 768
                float* __restrict__ cnew,
                bf16*  __restrict__ featc)  // nullable, row stride 2304
{
    __shared__ __align__(16) SMemU sm;
    __shared__ float gsh[GM * 3];

    const int m0 = blockIdx.y * GM;
    const int n0 = blockIdx.x * BN;
    const int jbase = n0 >> 2;
    const int tid  = threadIdx.x;
    const int lane = tid & 63;
    const int wave = tid >> 6;
    const int wm = (wave >> 1) * 16;   // 2x2 waves, each 16m x 64n
    const int wn = (wave & 1) * 64;
    const int q   = lane >> 4;
    const int r16 = lane & 15;

    f32x4 acc[4] = {};
    f32x4 accg = {};

    const int srow = lane >> 3;
    const int scolsw = ((lane & 7) ^ srow) * 8;

    for (int k0 = 0; k0 < 256; k0 += BK) {
        __syncthreads();
        // A: 32 rows = 4 chunks, one per wave
        lds_load16(A + (size_t)(m0 + wave * 8 + srow) * lda + k0 + scolsw,
                   &sm.s.As[wave * 8 * 64]);
        #pragma unroll
        for (int p = 0; p < 4; ++p) {
            int rbase = (wave * 4 + p) * 8;   // B: 128 rows = 16 chunks
            lds_load16(Wi + (size_t)(n0 + rbase + srow) * 256 + k0 + scolsw, &sm.s.Bs[rbase * 64]);
        }
        if (wave < 2)
            lds_load16(Wg + (size_t)(wave * 8 + srow) * 256 + k0 + scolsw, &sm.s.Bg[wave * 8 * 64]);
        __syncthreads();
        #pragma unroll
        for (int kk = 0; kk < 2; ++kk) {
            const int c = kk * 4 + q;
            frag8 af, bfr[4], bg;
            bg = *(const frag8*)&sm.s.Bg[r16 * 64 + ((c ^ (r16 & 7)) << 3)];
            {
                int R = wm + r16;
                af = *(const frag8*)&sm.s.As[R * 64 + ((c ^ (R & 7)) << 3)];
            }
            #pragma unroll
            for (int j = 0; j < 4; ++j) {
                int R = wn + j * 16 + r16;
                bfr[j] = *(const frag8*)&sm.s.Bs[R * 64 + ((c ^ (R & 7)) << 3)];
            }
            #pragma unroll
            for (int j = 0; j < 4; ++j)
                acc[j] = __builtin_amdgcn_mfma_f32_16x16x32_bf16(af, bfr[j], acc[j], 0, 0, 0);
            accg = __builtin_amdgcn_mfma_f32_16x16x32_bf16(af, bg, accg, 0, 0, 0);
        }
    }

    __syncthreads();   // staging reads done; sm union becomes ct
    // g values: waves with wn==0 (0 and 2) cover rows 0..31
    if (wn == 0 && r16 < 3) {
        #pragma unroll
        for (int rr = 0; rr < 4; ++rr) {
            int row = wm + q * 4 + rr;
            gsh[row * 3 + r16] = sigm(accg[rr] + ghc_l[(size_t)(m0 + row) * 9 + r16]);
        }
    }
    // dump C tile (rotate-swizzled float4 groups)
    #pragma unroll
    for (int rr = 0; rr < 4; ++rr) {
        int rowl = wm + q * 4 + rr;
        #pragma unroll
        for (int jr = 0; jr < 4; ++jr) {
            int col = wn + jr * 16 + r16;
            sm.ct[rowl * 128 + ((col + 4 * rowl) & 127)] = acc[jr][rr];
        }
    }
    __syncthreads();

    const int jj = tid & 31;
    const int r0 = (tid >> 5) * 4;
    const int j  = jbase + jj;
    const float vbif = bif[j], vbhf = bhf[j];
    const float vbii = bii[j], vbhi = bhi[j];
    const float vbio = bio[j], vbho = bho[j];
    const float vbic = bic[j];
    const float vbc0 = bhc[j], vbc1 = bhc[256 + j], vbc2 = bhc[512 + j];

    #pragma unroll
    for (int ri = 0; ri < 4; ++ri) {
        int rowl = r0 + ri;
        size_t b = m0 + rowl;
        float4 pre = *(float4*)&sm.ct[rowl * 128 + ((4 * jj + 4 * rowl) & 127)];
        float g0 = gsh[rowl * 3 + 0];
        float g1 = gsh[rowl * 3 + 1];
        float g2 = gsh[rowl * 3 + 2];
        float hgf = __bfloat162float(hg_l[b * 768 + j]);
        float hgi = __bfloat162float(hg_l[b * 768 + 256 + j]);
        float hgo = __bfloat162float(hg_l[b * 768 + 512 + j]);
        float ax0 = __bfloat162float(aux_l[b * 768 + j]);
        float ax1 = __bfloat162float(aux_l[b * 768 + 256 + j]);
        float ax2 = __bfloat162float(aux_l[b * 768 + 512 + j]);
        float f  = sigm(pre.x + vbif + hgf + vbhf);
        float ii = sigm(pre.y + vbii + hgi + vbhi);
        float o  = sigm(pre.z + vbio + hgo + vbho);
        float av = g0 * (ax0 + vbc0) + g1 * (ax1 + vbc1) + g2 * (ax2 + vbc2);
        float ct = tanhf(pre.w + vbic + av);
        float c  = f * cprev[b * 256 + j] + ii * ct;
        float h  = o * c;
        cnew[b * 256 + j] = c;
        hnew[b * 768 + j] = __float2bfloat16(h);
        if (featc) featc[b * 2304 + j] = __float2bfloat16(h);
    }
}

// ---------------- layer-0 gates from precomputed pre-acts ----------------
// 1024 blocks x 4 rows
__global__ __launch_bounds__(256)
void gates_pre(const bf16* __restrict__ ipre0i, const float* __restrict__ gin0,
               const float* __restrict__ ghc,
               const bf16* __restrict__ hg_l, const bf16* __restrict__ aux_l,
               const float* __restrict__ cprev,
               const float* __restrict__ bif, const float* __restrict__ bhf,
               const float* __restrict__ bii, const float* __restrict__ bhi,
               const float* __restrict__ bio, const float* __restrict__ bho,
               const float* __restrict__ bic, const float* __restrict__ bhc,
               bf16* __restrict__ hnew, float* __restrict__ cnew)
{
    const int j = threadIdx.x;
    const int b0 = blockIdx.x * 4;
    const float vbif = bif[j], vbhf = bhf[j];
    const float vbii = bii[j], vbhi = bhi[j];
    const float vbio = bio[j], vbho = bho[j];
    const float vbic = bic[j];
    const float vbc0 = bhc[j], vbc1 = bhc[256 + j], vbc2 = bhc[512 + j];

    #pragma unroll
    for (int r = 0; r < 4; ++r) {
        const size_t b = b0 + r;
        const bf16* ip4 = ipre0i + b * 1024 + 4 * j;
        float pf = __bfloat162float(ip4[0]);
        float pi = __bfloat162float(ip4[1]);
        float po = __bfloat162float(ip4[2]);
        float pc = __bfloat162float(ip4[3]);
        float g0 = sigm(gin0[b * 3 + 0] + ghc[b * 9 + 0]);
        float g1 = sigm(gin0[b * 3 + 1] + ghc[b * 9 + 1]);
        float g2 = sigm(gin0[b * 3 + 2] + ghc[b * 9 + 2]);
        float hgf = __bfloat162float(hg_l[b * 768 + j]);
        float hgi = __bfloat162float(hg_l[b * 768 + 256 + j]);
        float hgo = __bfloat162float(hg_l[b * 768 + 512 + j]);
        float ax0 = __bfloat162float(aux_l[b * 768 + j]);
        float ax1 = __bfloat162float(aux_l[b * 768 + 256 + j]);
        float ax2 = __bfloat162float(aux_l[b * 768 + 512 + j]);
        float f  = sigm(pf + vbif + hgf + vbhf);
        float ii = sigm(pi + vbii + hgi + vbhi);
        float o  = sigm(po + vbio + hgo + vbho);
        float av = g0 * (ax0 + vbc0) + g1 * (ax1 + vbc1) + g2 * (ax2 + vbc2);
        float ct = tanhf(pc + vbic + av);
        float c  = f * cprev[b * 256 + j] + ii * ct;
        float h  = o * c;
        cnew[b * 256 + j] = c;
        hnew[b * 768 + j] = __float2bfloat16(h);
    }
}

// out[b][n] = sigm(bias[n] + sum_z part[z][b][n]), n<44
__global__ __launch_bounds__(256)
void final_reduce(const float* __restrict__ part, const float* __restrict__ bl,
                  float* __restrict__ out)
{
    int idx = blockIdx.x * 256 + threadIdx.x;
    if (idx >= 4096 * 44) return;
    int b = idx / 44, n = idx - b * 44;
    float s = bl[n];
    #pragma unroll
    for (int z = 0; z < 12; ++z) s += part[(size_t)z * 4096 * 64 + (size_t)b * 64 + n];
    out[idx] = sigm(s);
}

// ---------------- single merged prep kernel ----------------
__global__ __launch_bounds__(256)
void prep_all(const float* __restrict__ Wi_f, const float* __restrict__ Wi_i,
              const float* __restrict__ Wi_o, const float* __restrict__ Wi_c,
              const float* __restrict__ Wh_f, const float* __restrict__ Wh_i,
              const float* __restrict__ Wh_o, const float* __restrict__ Wh_c,
              const float* __restrict__ Wi_g, const float* __restrict__ Wh_g,
              const float* __restrict__ W_last, const float* __restrict__ x,
              const float* __restrict__ hidden0, const float* __restrict__ current0,
              bf16* __restrict__ WiCatI, bf16* __restrict__ WhFIO,
              bf16* __restrict__ WhCb, bf16* __restrict__ Wgb,
              bf16* __restrict__ WgH, bf16* __restrict__ Wlb,
              bf16* __restrict__ xb, bf16* __restrict__ hcat, float* __restrict__ c0)
{
    int idx = blockIdx.x * 256 + threadIdx.x;
    if (idx < 786432) {                                   // WiCatI: n = 4j+gate
        int k = idx & 255, n = (idx >> 8) & 1023, l = idx >> 18;
        int j = n >> 2, g = n & 3;
        const float* src = (g == 0) ? Wi_f : (g == 1) ? Wi_i : (g == 2) ? Wi_o : Wi_c;
        WiCatI[idx] = __float2bfloat16(src[l * 65536 + j * 256 + k]);
        return;
    }
    idx -= 786432;
    if (idx < 589824) {                                   // WhFIO
        int k = idx & 255, n = (idx >> 8) % 768, l = idx / 196608;
        const float* src = (n < 256) ? Wh_f : (n < 512) ? Wh_i : Wh_o;
        WhFIO[idx] = __float2bfloat16(src[l * 65536 + (n & 255) * 256 + k]);
        return;
    }
    idx -= 589824;
    if (idx < 1769472) {                                  // WhCb convert
        WhCb[idx] = __float2bfloat16(Wh_c[idx]);
        return;
    }
    idx -= 1769472;
    if (idx < 12288) {                                    // Wgb [3][16][256]
        int k = idx & 255, r = (idx >> 8) & 15, l = idx >> 12;
        Wgb[idx] = (r < 3) ? __float2bfloat16(Wi_g[l * 768 + r * 256 + k])
                           : __float2bfloat16(0.f);
        return;
    }
    idx -= 12288;
    if (idx < 36864) {                                    // WgH [3][16][768]
        int k = idx % 768, r = (idx / 768) & 15, l = idx / (16 * 768);
        WgH[idx] = (r < 3) ? __float2bfloat16(Wh_g[(l * 3 + r) * 768 + k])
                           : __float2bfloat16(0.f);
        return;
    }
    idx -= 36864;
    if (idx < 294912) {                                   // Wlb [128][2304]
        int k = idx % 2304, n = idx / 2304;
        Wlb[idx] = (n < 44) ? __float2bfloat16(W_last[n * 2304 + k])
                            : __float2bfloat16(0.f);
        return;
    }
    idx -= 294912;
    if (idx < 1048576) {                                  // xb convert
        xb[idx] = __float2bfloat16(x[idx]);
        return;
    }
    idx -= 1048576;
    if (idx < 3145728) {                                  // state: hcat + c0
        int j = idx & 255, b = (idx >> 8) & 4095, l = idx >> 20;
        hcat[(size_t)b * 768 + l * 256 + j] = __float2bfloat16(hidden0[idx]);
        c0[idx] = current0[idx];
    }
}

extern "C" void kernel_launch(void* const* d_in, const int* in_sizes, int n_in,
                              void* d_out, int out_size, void* d_ws, size_t ws_size,
                              hipStream_t stream)
{
    (void)in_sizes; (void)n_in; (void)out_size; (void)ws_size;
    const float* x        = (const float*)d_in[0];
    const float* hidden0  = (const float*)d_in[1];
    const float* current0 = (const float*)d_in[2];
    const float* Wi_f = (const float*)d_in[3];  const float* bi_f = (const float*)d_in[4];
    const float* Wi_i = (const float*)d_in[5];  const float* bi_i = (const float*)d_in[6];
    const float* Wi_o = (const float*)d_in[7];  const float* bi_o = (const float*)d_in[8];
    const float* Wi_c = (const float*)d_in[9];  const float* bi_c = (const float*)d_in[10];
    const float* Wi_g = (const float*)d_in[11]; const float* bi_g = (const float*)d_in[12];
    const float* Wh_f = (const float*)d_in[13]; const float* bh_f = (const float*)d_in[14];
    const float* Wh_i = (const float*)d_in[15]; const float* bh_i = (const float*)d_in[16];
    const float* Wh_o = (const float*)d_in[17]; const float* bh_o = (const float*)d_in[18];
    const float* Wh_g = (const float*)d_in[19]; const float* bh_g = (const float*)d_in[20];
    const float* Wh_c = (const float*)d_in[21]; const float* bh_c = (const float*)d_in[22];
    const float* W_last = (const float*)d_in[23]; const float* b_last = (const float*)d_in[24];

    char* p = (char*)d_ws;
    bf16* WiCatI = (bf16*)p; p += (size_t)3 * 1024 * 256 * 2;
    bf16* WhFIO  = (bf16*)p; p += (size_t)3 * 768 * 256 * 2;
    bf16* WhCb   = (bf16*)p; p += (size_t)3 * 768 * 768 * 2;
    bf16* Wgb    = (bf16*)p; p += (size_t)3 * 16 * 256 * 2;
    bf16* WgH    = (bf16*)p; p += (size_t)3 * 16 * 768 * 2;
    bf16* Wlb    = (bf16*)p; p += (size_t)128 * 2304 * 2;
    bf16* xb     = (bf16*)p; p += (size_t)4096 * 256 * 2;
    bf16* ipre0i = (bf16*)p; p += (size_t)4096 * 1024 * 2;
    float* gin0  = (float*)p; p += (size_t)4096 * 3 * 4;
    bf16* hb0    = (bf16*)p; p += (size_t)4096 * 768 * 2;
    bf16* hb1    = (bf16*)p; p += (size_t)4096 * 768 * 2;
    float* cb0   = (float*)p; p += (size_t)3 * 4096 * 256 * 4;
    float* cb1   = (float*)p; p += (size_t)3 * 4096 * 256 * 4;
    bf16* hgb    = (bf16*)p; p += (size_t)3 * 4096 * 768 * 2;
    bf16* auxb   = (bf16*)p; p += (size_t)3 * 4096 * 768 * 2;
    float* gh    = (float*)p; p += (size_t)4096 * 9 * 4;
    bf16* feat   = (bf16*)p; p += (size_t)4096 * 2304 * 2;
    float* partf = (float*)p; p += (size_t)12 * 4096 * 64 * 4;

    // one merged prep launch: 7,684,096 elements
    prep_all<<<30017, 256, 0, stream>>>(
        Wi_f, Wi_i, Wi_o, Wi_c, Wh_f, Wh_i, Wh_o, Wh_c, Wi_g, Wh_g, W_last, x,
        hidden0, current0,
        WiCatI, WhFIO, WhCb, Wgb, WgH, Wlb, xb, hb0, cb0);

    // hoisted layer-0 input-side work (x constant across t); gin0 rides as Bg fragment
    gemm_bt64<<<dim3(8, 64, 1), 256, 0, stream>>>(xb, 256, 0, WiCatI, 256, 0,
                                                  ipre0i, 1024, 0, 256, 1, 0,
                                                  Wgb, gin0);

    for (int t = 0; t < 10; ++t) {
        bf16* hprev = (t & 1) ? hb1 : hb0;
        bf16* hnew  = (t & 1) ? hb0 : hb1;
        float* cprev = (t & 1) ? cb1 : cb0;
        float* cnew  = (t & 1) ? cb0 : cb1;

        gemm_hidden<<<dim3(36, 32), 256, 0, stream>>>(
            hprev, WhFIO, WhCb, WgH, bi_g, bh_g, hgb, auxb, gh);

        gates_pre<<<1024, 256, 0, stream>>>(
            ipre0i, gin0, gh,
            hgb, auxb, cprev,
            bi_f, bh_f, bi_i, bh_i, bi_o, bh_o, bi_c, bh_c,
            hnew, cnew);

        for (int l = 1; l < 3; ++l) {
            gemm_gates<<<dim3(8, 128), 256, 0, stream>>>(
                (const bf16*)(hnew + (l - 1) * 256), 768,
                WiCatI + (size_t)l * 1024 * 256,
                Wgb + (size_t)l * 16 * 256,
                hgb + (size_t)l * 4096 * 768,
                auxb + (size_t)l * 4096 * 768,
                gh + l * 3,
                cprev + (size_t)l * 4096 * 256,
                bi_f + l * 256, bh_f + l * 256,
                bi_i + l * 256, bh_i + l * 256,
                bi_o + l * 256, bh_o + l * 256,
                bi_c + l * 256, bh_c + l * 768,
                hnew + l * 256,
                cnew + (size_t)l * 4096 * 256,
                (l == 2 && t < 9) ? (feat + (size_t)t * 256) : (bf16*)nullptr);
        }
    }

    // final: K-split feat[4096,2304] @ Wlb[128,2304]^T into 12 partials of K=192
    gemm_bt64<<<dim3(1, 64, 12), 256, 0, stream>>>(
        feat, 2304, 192, Wlb, 2304, 192,
        partf, 64, (long long)4096 * 64, 192, 3, 64,
        nullptr, nullptr);
    final_reduce<<<704, 256, 0, stream>>>(partf, b_last, (float*)d_out);
}